// Round 10
// baseline (399.037 us; speedup 1.0000x reference)
//
#include <hip/hip_runtime.h>
#include <math.h>

#define B_  4
#define L_  1024
#define DM  1024
#define DI  1024
#define DS  16
#define DR  64
#define DCV 4
#define NH  4
#define DK  256

#define NCH 32         // scan time-chunks
#define CHL (L_ / NCH) // 32 steps per chunk

typedef __attribute__((ext_vector_type(8))) short short8;
typedef __attribute__((ext_vector_type(4))) float floatx4;

static __device__ __forceinline__ unsigned short f2bf(float f) {
    unsigned int u = __float_as_uint(f);
    u += 0x7fffu + ((u >> 16) & 1u);
    return (unsigned short)(u >> 16);
}
static __device__ __forceinline__ float bf2f(unsigned short s) {
    return __uint_as_float(((unsigned int)s) << 16);
}

#define GLL(gp, lp) __builtin_amdgcn_global_load_lds( \
        (const __attribute__((address_space(1))) void*)(gp), \
        (__attribute__((address_space(3))) void*)(lp), 16, 0, 0)

// XCD-aware rectangular tile remap (T1). Bijective when 2|gx and 4|gy.
static __device__ __forceinline__ void xcd_rect(int gx, int gy, int& tx, int& ty)
{
    int n = blockIdx.x + gx * blockIdx.y;
    if ((gx & 1) == 0 && (gy & 3) == 0) {
        int xcd = n & 7, j = n >> 3;
        int hx = gx >> 1, qy = gy >> 2;
        tx = (xcd & 1) * hx + (j % hx);
        ty = (xcd >> 1) * qy + (j / hx);
    } else {
        tx = blockIdx.x; ty = blockIdx.y;
    }
}

// ---------------------------------------------------------------------------
// prep: fused conv+silu (region 0, scalar; bf16-only u output), x cast,
// 6 row-major weight casts, and a transposed bf16 cast of in_proj_w (for
// the Q-weight fold: Q = x @ (wq @ W_in)^T -> combo GEMM needs W_in^T).
// Regions: [0,16384) conv | [ ,+4096) x cast | 6 weights | [ ,+1024) transpose
// ---------------------------------------------------------------------------
struct PrepArgs {
    const float* xx; const float* cw; const float* cb;
    unsigned short* ub;
    const float* xs; unsigned short* xd;
    const float* s[6]; unsigned short* d[6];
    int n[6];   // dest elements (mult of 1024)
    int ns[6];  // source elements (<= n, zero-pad past)
    const float* tsrc; unsigned short* tdst;  // in_proj_w -> bf16 transposed
};

__global__ __launch_bounds__(256) void prep(PrepArgs pa)
{
    __shared__ unsigned short tl[32][36];
    int bid = blockIdx.x, tid = threadIdx.x;
    if (bid < 16384) {
        // conv + silu (scalar, 1 elem/thread); u stored bf16 only
        int idx = bid * 256 + tid;
        int d = idx & (DI - 1);
        int l = (idx >> 10) & (L_ - 1);
        int b = idx >> 20;
        const float* xb = pa.xx + (size_t)b * L_ * DI + d;
        float z = pa.cb[d];
#pragma unroll
        for (int j = 0; j < DCV; j++) {
            int t = l - (DCV - 1) + j;
            if (t >= 0) z += xb[(size_t)t * DI] * pa.cw[d * DCV + j];
        }
        float v = z / (1.0f + __expf(-z));
        pa.ub[idx] = f2bf(v);
        return;
    }
    bid -= 16384;
    if (bid < 4096) {
        int i = (bid * 256 + tid) * 4;
        float4 v = *(const float4*)(pa.xs + i);
        ushort4 o;
        o.x = f2bf(v.x); o.y = f2bf(v.y); o.z = f2bf(v.z); o.w = f2bf(v.w);
        *(ushort4*)(pa.xd + i) = o;
        return;
    }
    bid -= 4096;
#pragma unroll
    for (int r = 0; r < 6; r++) {
        int nb = pa.n[r] >> 10;
        if (bid < nb) {
            int i = (bid * 256 + tid) * 4;
            int ns = pa.ns[r];
            const float* s = pa.s[r];
            ushort4 o;
            if (i + 4 <= ns) {
                float4 v = *(const float4*)(s + i);
                o.x = f2bf(v.x); o.y = f2bf(v.y); o.z = f2bf(v.z); o.w = f2bf(v.w);
            } else {
                float v[4];
#pragma unroll
                for (int j = 0; j < 4; j++) v[j] = (i + j < ns) ? s[i + j] : 0.f;
                o.x = f2bf(v[0]); o.y = f2bf(v[1]); o.z = f2bf(v[2]); o.w = f2bf(v[3]);
            }
            *(ushort4*)(pa.d[r] + i) = o;
            return;
        }
        bid -= nb;
    }
    // transposed cast region: bid in [0,1024), one 32x32 tile per block
    // tdst[n][j] = tsrc[j][n], bf16
    int j0 = (bid >> 5) * 32;
    int n0 = (bid & 31) * 32;
    int r = tid >> 3, c4 = (tid & 7) * 4;
    float4 v = *(const float4*)(pa.tsrc + (size_t)(j0 + r) * 1024 + n0 + c4);
    tl[r][c4 + 0] = f2bf(v.x); tl[r][c4 + 1] = f2bf(v.y);
    tl[r][c4 + 2] = f2bf(v.z); tl[r][c4 + 3] = f2bf(v.w);
    __syncthreads();
    ushort4 o;
    o.x = tl[c4 + 0][r]; o.y = tl[c4 + 1][r];
    o.z = tl[c4 + 2][r]; o.w = tl[c4 + 3][r];
    *(ushort4*)(pa.tdst + (size_t)(n0 + r) * 1024 + j0 + c4) = o;
}

// ---------------------------------------------------------------------------
// out += p1 + bias (split-K reduction for the final projection)
// ---------------------------------------------------------------------------
__global__ __launch_bounds__(256) void addout(
    float* __restrict__ out, const float* __restrict__ p1,
    const float* __restrict__ bias)
{
    int i = (blockIdx.x * 256 + threadIdx.x) * 4;
    int col = i & 1023;
    float4 a = *(const float4*)(out + i);
    float4 b = *(const float4*)(p1 + i);
    float4 bb = *(const float4*)(bias + col);
    a.x += b.x + bb.x; a.y += b.y + bb.y;
    a.z += b.z + bb.z; a.w += b.w + bb.w;
    *(float4*)(out + i) = a;
}

// ---------------------------------------------------------------------------
// Multi-descriptor bf16 MFMA GEMM: per z, C = act(A @ W^T * scale + bias)
// mode & 3: 0 = fp32 out, 1 = bf16 out, 2 = both. mode & 4: softplus.
// R3-proven: 3-stage pipeline, counted vmcnt (T3/T4) + LDS chunk-XOR
// swizzle (T2, conflicts measured 0) + setprio (T5) + XCD rect remap (T1).
// ---------------------------------------------------------------------------
struct GDesc {
    const unsigned short* A;
    const unsigned short* W;
    const float* bias;
    float* Cf;
    unsigned short* Cb;
    int K, lda, ldw, ldc, ldc2;
    int mode;
    float scale;
    int gx, gy;
};
struct GArgs { GDesc g[3]; };

__global__ __launch_bounds__(256) void gemm_multi(GArgs ga)
{
    GDesc g = ga.g[blockIdx.z];
    int bx, by;
    xcd_rect(gridDim.x, gridDim.y, bx, by);
    if (bx >= g.gx || by >= g.gy) return;

    __shared__ __align__(16) unsigned short Asm[3][128 * 32];
    __shared__ __align__(16) unsigned short Bsm[3][128 * 32];

    int tid = threadIdx.x;
    int wid = tid >> 6;
    int lane = tid & 63;
    int wm = wid & 1, wn = wid >> 1;
    int lr = lane & 15, quad = lane >> 4;
    int sq = quad ^ ((lr >> 1) & 3);   // swizzled 16B-chunk index for reads

    const unsigned short* Ab = g.A + (size_t)by * 128 * g.lda;
    const unsigned short* Wb = g.W + (size_t)bx * 128 * g.ldw;

    int srow = tid >> 2;
    int scol = ((tid & 3) ^ ((tid >> 3) & 3)) * 8;  // pre-swizzled global chunk
    const unsigned short* Ap = Ab + (size_t)srow * g.lda + scol;
    const unsigned short* Wp = Wb + (size_t)srow * g.ldw + scol;

    int lbase = (wid * 16) * 32;

    floatx4 acc[4][4];
#pragma unroll
    for (int i = 0; i < 4; i++)
#pragma unroll
        for (int j = 0; j < 4; j++) acc[i][j] = (floatx4){0.f, 0.f, 0.f, 0.f};

#define STAGE_M(buf) do { \
        GLL(Ap, &Asm[buf][lbase]); \
        GLL(Ap + (size_t)64 * g.lda, &Asm[buf][lbase + 64 * 32]); \
        GLL(Wp, &Bsm[buf][lbase]); \
        GLL(Wp + (size_t)64 * g.ldw, &Bsm[buf][lbase + 64 * 32]); \
        Ap += 32; Wp += 32; \
    } while (0)

    int nK = g.K >> 5;
    STAGE_M(0);
    if (nK > 1) STAGE_M(1);

    int cur = 0, stg = 2;
    for (int k = 0; k < nK - 1; k++) {
        asm volatile("s_waitcnt vmcnt(4)" ::: "memory");
        __builtin_amdgcn_s_barrier();
        __builtin_amdgcn_sched_barrier(0);

        short8 af[4], bf[4];
#pragma unroll
        for (int mt = 0; mt < 4; mt++)
            af[mt] = *(const short8*)&Asm[cur][(wm * 64 + mt * 16 + lr) * 32 + sq * 8];
#pragma unroll
        for (int nt = 0; nt < 4; nt++)
            bf[nt] = *(const short8*)&Bsm[cur][(wn * 64 + nt * 16 + lr) * 32 + sq * 8];

        if (k + 2 < nK) {
            STAGE_M(stg);
            stg = (stg == 2) ? 0 : stg + 1;
        }

        __builtin_amdgcn_s_setprio(1);
#pragma unroll
        for (int mt = 0; mt < 4; mt++)
#pragma unroll
            for (int nt = 0; nt < 4; nt++)
                acc[mt][nt] = __builtin_amdgcn_mfma_f32_16x16x32_bf16(
                    af[mt], bf[nt], acc[mt][nt], 0, 0, 0);
        __builtin_amdgcn_s_setprio(0);
        cur = (cur == 2) ? 0 : cur + 1;
    }
    {
        asm volatile("s_waitcnt vmcnt(0)" ::: "memory");
        __builtin_amdgcn_s_barrier();
        __builtin_amdgcn_sched_barrier(0);

        short8 af[4], bf[4];
#pragma unroll
        for (int mt = 0; mt < 4; mt++)
            af[mt] = *(const short8*)&Asm[cur][(wm * 64 + mt * 16 + lr) * 32 + sq * 8];
#pragma unroll
        for (int nt = 0; nt < 4; nt++)
            bf[nt] = *(const short8*)&Bsm[cur][(wn * 64 + nt * 16 + lr) * 32 + sq * 8];
        __builtin_amdgcn_s_setprio(1);
#pragma unroll
        for (int mt = 0; mt < 4; mt++)
#pragma unroll
            for (int nt = 0; nt < 4; nt++)
                acc[mt][nt] = __builtin_amdgcn_mfma_f32_16x16x32_bf16(
                    af[mt], bf[nt], acc[mt][nt], 0, 0, 0);
        __builtin_amdgcn_s_setprio(0);
    }
#undef STAGE_M

    int bm = by * 128, bn = bx * 128;
    int m = g.mode & 3;
#pragma unroll
    for (int mt = 0; mt < 4; mt++) {
#pragma unroll
        for (int nt = 0; nt < 4; nt++) {
            int row0 = bm + wm * 64 + mt * 16 + quad * 4;
            int col = bn + wn * 64 + nt * 16 + lr;
            float bv = g.bias ? g.bias[col] : 0.f;
#pragma unroll
            for (int i = 0; i < 4; i++) {
                float v = acc[mt][nt][i] * g.scale + bv;
                if (g.mode & 4) v = (v > 15.f) ? v : log1pf(__expf(v));
                if (m == 0) {
                    g.Cf[(size_t)(row0 + i) * g.ldc + col] = v;
                } else if (m == 1) {
                    g.Cb[(size_t)(row0 + i) * g.ldc + col] = f2bf(v);
                } else {
                    g.Cf[(size_t)(row0 + i) * g.ldc + col] = v;
                    g.Cb[(size_t)(row0 + i) * g.ldc2 + col] = f2bf(v);
                }
            }
        }
    }
}

// ---------------------------------------------------------------------------
// Batched-strided bf16 MFMA GEMM (attention): z -> b=z>>2, h=z&3
// Same 3-stage counted-vmcnt + swizzle + setprio K-loop, + XCD rect remap.
// ---------------------------------------------------------------------------
__global__ __launch_bounds__(256) void gemm_batched(
    const unsigned short* __restrict__ A, const unsigned short* __restrict__ W,
    unsigned short* __restrict__ C,
    int K, int lda, int ldw, int ldc,
    long long sA1, long long sA2, long long sW1, long long sW2,
    long long sC1, long long sC2, float scale)
{
    __shared__ __align__(16) unsigned short Asm[3][128 * 32];
    __shared__ __align__(16) unsigned short Bsm[3][128 * 32];

    int bx, by;
    xcd_rect(gridDim.x, gridDim.y, bx, by);

    int z = blockIdx.z;
    long long bq = z >> 2, hq = z & 3;
    int tid = threadIdx.x;
    int wid = tid >> 6;
    int lane = tid & 63;
    int wm = wid & 1, wn = wid >> 1;
    int lr = lane & 15, quad = lane >> 4;
    int sq = quad ^ ((lr >> 1) & 3);

    const unsigned short* Ab = A + bq * sA1 + hq * sA2 + (size_t)by * 128 * lda;
    const unsigned short* Wb = W + bq * sW1 + hq * sW2 + (size_t)bx * 128 * ldw;

    int srow = tid >> 2;
    int scol = ((tid & 3) ^ ((tid >> 3) & 3)) * 8;
    const unsigned short* Ap = Ab + (size_t)srow * lda + scol;
    const unsigned short* Wp = Wb + (size_t)srow * ldw + scol;

    int lbase = (wid * 16) * 32;

    floatx4 acc[4][4];
#pragma unroll
    for (int i = 0; i < 4; i++)
#pragma unroll
        for (int j = 0; j < 4; j++) acc[i][j] = (floatx4){0.f, 0.f, 0.f, 0.f};

#define STAGE_B(buf) do { \
        GLL(Ap, &Asm[buf][lbase]); \
        GLL(Ap + (size_t)64 * lda, &Asm[buf][lbase + 64 * 32]); \
        GLL(Wp, &Bsm[buf][lbase]); \
        GLL(Wp + (size_t)64 * ldw, &Bsm[buf][lbase + 64 * 32]); \
        Ap += 32; Wp += 32; \
    } while (0)

    int nK = K >> 5;
    STAGE_B(0);
    if (nK > 1) STAGE_B(1);

    int cur = 0, stg = 2;
    for (int k = 0; k < nK - 1; k++) {
        asm volatile("s_waitcnt vmcnt(4)" ::: "memory");
        __builtin_amdgcn_s_barrier();
        __builtin_amdgcn_sched_barrier(0);

        short8 af[4], bf[4];
#pragma unroll
        for (int mt = 0; mt < 4; mt++)
            af[mt] = *(const short8*)&Asm[cur][(wm * 64 + mt * 16 + lr) * 32 + sq * 8];
#pragma unroll
        for (int nt = 0; nt < 4; nt++)
            bf[nt] = *(const short8*)&Bsm[cur][(wn * 64 + nt * 16 + lr) * 32 + sq * 8];

        if (k + 2 < nK) {
            STAGE_B(stg);
            stg = (stg == 2) ? 0 : stg + 1;
        }

        __builtin_amdgcn_s_setprio(1);
#pragma unroll
        for (int mt = 0; mt < 4; mt++)
#pragma unroll
            for (int nt = 0; nt < 4; nt++)
                acc[mt][nt] = __builtin_amdgcn_mfma_f32_16x16x32_bf16(
                    af[mt], bf[nt], acc[mt][nt], 0, 0, 0);
        __builtin_amdgcn_s_setprio(0);
        cur = (cur == 2) ? 0 : cur + 1;
    }
    {
        asm volatile("s_waitcnt vmcnt(0)" ::: "memory");
        __builtin_amdgcn_s_barrier();
        __builtin_amdgcn_sched_barrier(0);

        short8 af[4], bf[4];
#pragma unroll
        for (int mt = 0; mt < 4; mt++)
            af[mt] = *(const short8*)&Asm[cur][(wm * 64 + mt * 16 + lr) * 32 + sq * 8];
#pragma unroll
        for (int nt = 0; nt < 4; nt++)
            bf[nt] = *(const short8*)&Bsm[cur][(wn * 64 + nt * 16 + lr) * 32 + sq * 8];
        __builtin_amdgcn_s_setprio(1);
#pragma unroll
        for (int mt = 0; mt < 4; mt++)
#pragma unroll
            for (int nt = 0; nt < 4; nt++)
                acc[mt][nt] = __builtin_amdgcn_mfma_f32_16x16x32_bf16(
                    af[mt], bf[nt], acc[mt][nt], 0, 0, 0);
        __builtin_amdgcn_s_setprio(0);
    }
#undef STAGE_B

    long long coff = bq * sC1 + hq * sC2;
    int bm = by * 128, bn = bx * 128;
    unsigned short* Cb = C + coff;

#pragma unroll
    for (int mt = 0; mt < 4; mt++) {
#pragma unroll
        for (int nt = 0; nt < 4; nt++) {
            int row0 = bm + wm * 64 + mt * 16 + quad * 4;
            int col = bn + wn * 64 + nt * 16 + lr;
#pragma unroll
            for (int i = 0; i < 4; i++)
                Cb[(size_t)(row0 + i) * ldc + col] = f2bf(acc[mt][nt][i] * scale);
        }
    }
}

// ---------------------------------------------------------------------------
// Scan phase A: one thread = (b,d,chunk), 16 states in registers.
// u is read as bf16 (single stored copy).
// ---------------------------------------------------------------------------
__global__ __launch_bounds__(256) void scan_a(
    const float* __restrict__ delta, const unsigned short* __restrict__ u,
    const float* __restrict__ xdbl, const float* __restrict__ A_log,
    float* __restrict__ Hc, float* __restrict__ sumdv)
{
    int gid = blockIdx.x * 256 + threadIdx.x;
    int c = gid >> 12;
    int bd = gid & 4095;
    int b = bd >> 10, d = bd & 1023;

    float a[16];
#pragma unroll
    for (int j = 0; j < 4; j++) {
        float4 al = *(const float4*)(A_log + d * 16 + j * 4);
        a[j * 4 + 0] = -__expf(al.x); a[j * 4 + 1] = -__expf(al.y);
        a[j * 4 + 2] = -__expf(al.z); a[j * 4 + 3] = -__expf(al.w);
    }
    float h[16];
#pragma unroll
    for (int n = 0; n < 16; n++) h[n] = 0.f;
    float sd = 0.f;

    int t0 = c * CHL;
    const float* dp = delta + ((size_t)(b * L_) + t0) * DI + d;
    const unsigned short* up = u + ((size_t)(b * L_) + t0) * DI + d;
    const float* xp = xdbl + ((size_t)(b * L_) + t0) * 128;

#pragma unroll 4
    for (int t = 0; t < CHL; t++) {
        float dv = dp[t * DI];
        float uv = bf2f(up[t * DI]);
        float duv = dv * uv;
        sd += dv;
        float Bv[16];
#pragma unroll
        for (int j = 0; j < 4; j++) {
            float4 bq = *(const float4*)(xp + t * 128 + 64 + j * 4);
            Bv[j * 4 + 0] = bq.x; Bv[j * 4 + 1] = bq.y;
            Bv[j * 4 + 2] = bq.z; Bv[j * 4 + 3] = bq.w;
        }
#pragma unroll
        for (int n = 0; n < 16; n++)
            h[n] = __expf(dv * a[n]) * h[n] + duv * Bv[n];
    }

    float* hp = Hc + ((size_t)c * 4096 + bd) * 16;
#pragma unroll
    for (int j = 0; j < 4; j++)
        *(float4*)(hp + j * 4) = make_float4(h[j * 4], h[j * 4 + 1], h[j * 4 + 2], h[j * 4 + 3]);
    sumdv[c * 4096 + bd] = sd;
}

// ---------------------------------------------------------------------------
// Scan phase B: in-place combine — Hc[c][bd][*] becomes chunk START state
// ---------------------------------------------------------------------------
__global__ __launch_bounds__(256) void scan_b(
    float* __restrict__ Hc, const float* __restrict__ sumdv,
    const float* __restrict__ A_log)
{
    int bd = blockIdx.x * 256 + threadIdx.x;
    int d = bd & 1023;

    float a[16];
#pragma unroll
    for (int j = 0; j < 4; j++) {
        float4 al = *(const float4*)(A_log + d * 16 + j * 4);
        a[j * 4 + 0] = -__expf(al.x); a[j * 4 + 1] = -__expf(al.y);
        a[j * 4 + 2] = -__expf(al.z); a[j * 4 + 3] = -__expf(al.w);
    }
    float H[16];
#pragma unroll
    for (int n = 0; n < 16; n++) H[n] = 0.f;

    for (int c = 0; c < NCH; c++) {
        float* hp = Hc + ((size_t)c * 4096 + bd) * 16;
        float sdv = sumdv[c * 4096 + bd];
        float hc[16];
#pragma unroll
        for (int j = 0; j < 4; j++) {
            float4 q = *(const float4*)(hp + j * 4);
            hc[j * 4 + 0] = q.x; hc[j * 4 + 1] = q.y; hc[j * 4 + 2] = q.z; hc[j * 4 + 3] = q.w;
        }
#pragma unroll
        for (int j = 0; j < 4; j++)
            *(float4*)(hp + j * 4) = make_float4(H[j * 4], H[j * 4 + 1], H[j * 4 + 2], H[j * 4 + 3]);
#pragma unroll
        for (int n = 0; n < 16; n++)
            H[n] = __expf(a[n] * sdv) * H[n] + hc[n];
    }
}

// ---------------------------------------------------------------------------
// Scan phase C: re-run chunk from start state, emit y (bf16). u read bf16.
// ---------------------------------------------------------------------------
__global__ __launch_bounds__(256) void scan_c(
    const float* __restrict__ delta, const unsigned short* __restrict__ u,
    const float* __restrict__ xdbl, const float* __restrict__ A_log,
    const float* __restrict__ Dv, const float* __restrict__ Hstart,
    unsigned short* __restrict__ y)
{
    int gid = blockIdx.x * 256 + threadIdx.x;
    int c = gid >> 12;
    int bd = gid & 4095;
    int b = bd >> 10, d = bd & 1023;

    float a[16];
#pragma unroll
    for (int j = 0; j < 4; j++) {
        float4 al = *(const float4*)(A_log + d * 16 + j * 4);
        a[j * 4 + 0] = -__expf(al.x); a[j * 4 + 1] = -__expf(al.y);
        a[j * 4 + 2] = -__expf(al.z); a[j * 4 + 3] = -__expf(al.w);
    }
    float h[16];
    const float* hp = Hstart + ((size_t)c * 4096 + bd) * 16;
#pragma unroll
    for (int j = 0; j < 4; j++) {
        float4 q = *(const float4*)(hp + j * 4);
        h[j * 4 + 0] = q.x; h[j * 4 + 1] = q.y; h[j * 4 + 2] = q.z; h[j * 4 + 3] = q.w;
    }
    float Dd = Dv[d];

    int t0 = c * CHL;
    const float* dp = delta + ((size_t)(b * L_) + t0) * DI + d;
    const unsigned short* up = u + ((size_t)(b * L_) + t0) * DI + d;
    const float* xp = xdbl + ((size_t)(b * L_) + t0) * 128;
    unsigned short* yp = y + ((size_t)(b * L_) + t0) * DI + d;

#pragma unroll 4
    for (int t = 0; t < CHL; t++) {
        float dv = dp[t * DI];
        float uv = bf2f(up[t * DI]);
        float duv = dv * uv;
        float Bv[16], Cv[16];
#pragma unroll
        for (int j = 0; j < 4; j++) {
            float4 bq = *(const float4*)(xp + t * 128 + 64 + j * 4);
            Bv[j * 4 + 0] = bq.x; Bv[j * 4 + 1] = bq.y;
            Bv[j * 4 + 2] = bq.z; Bv[j * 4 + 3] = bq.w;
            float4 cq = *(const float4*)(xp + t * 128 + 80 + j * 4);
            Cv[j * 4 + 0] = cq.x; Cv[j * 4 + 1] = cq.y;
            Cv[j * 4 + 2] = cq.z; Cv[j * 4 + 3] = cq.w;
        }
        float ys = 0.f;
#pragma unroll
        for (int n = 0; n < 16; n++) {
            h[n] = __expf(dv * a[n]) * h[n] + duv * Bv[n];
            ys += h[n] * Cv[n];
        }
        yp[t * DI] = f2bf(ys + uv * Dd);
    }
}

// ---------------------------------------------------------------------------
// Merged: row softmax over S (blocks 0..4095) + V->VT transpose
// (blocks 4096..8191). Independent work, one dispatch.
// ---------------------------------------------------------------------------
__global__ __launch_bounds__(256) void softmax_transpose(
    unsigned short* __restrict__ S,
    const unsigned short* __restrict__ V, unsigned short* __restrict__ VT)
{
    __shared__ unsigned short tl[32][36];
    int bid = blockIdx.x;
    if (bid < 4096) {
        int row = bid * 4 + (threadIdx.x >> 6);
        int lane = threadIdx.x & 63;
        unsigned short* p = S + (size_t)row * 1024;

        float v[16];
#pragma unroll
        for (int ch = 0; ch < 4; ch++) {
            ushort4 u4 = *(const ushort4*)(p + ch * 256 + lane * 4);
            v[ch * 4 + 0] = bf2f(u4.x); v[ch * 4 + 1] = bf2f(u4.y);
            v[ch * 4 + 2] = bf2f(u4.z); v[ch * 4 + 3] = bf2f(u4.w);
        }
        float m = -1e30f;
#pragma unroll
        for (int i = 0; i < 16; i++) m = fmaxf(m, v[i]);
#pragma unroll
        for (int off = 32; off >= 1; off >>= 1) m = fmaxf(m, __shfl_xor(m, off));
        float s = 0.f;
#pragma unroll
        for (int i = 0; i < 16; i++) { v[i] = __expf(v[i] - m); s += v[i]; }
#pragma unroll
        for (int off = 32; off >= 1; off >>= 1) s += __shfl_xor(s, off);
        float inv = 1.0f / s;
#pragma unroll
        for (int ch = 0; ch < 4; ch++) {
            ushort4 o;
            o.x = f2bf(v[ch * 4 + 0] * inv); o.y = f2bf(v[ch * 4 + 1] * inv);
            o.z = f2bf(v[ch * 4 + 2] * inv); o.w = f2bf(v[ch * 4 + 3] * inv);
            *(ushort4*)(p + ch * 256 + lane * 4) = o;
        }
        return;
    }
    int tb = bid - 4096;
    int bh = tb >> 8;
    int rem = tb & 255;
    int d0 = (rem >> 5) * 32;
    int l0 = (rem & 31) * 32;
    int b = bh >> 2, h = bh & 3;
    int tid = threadIdx.x;
    int r = tid >> 3, c4 = (tid & 7) * 4;

    const unsigned short* src = V + ((size_t)(b * L_ + l0 + r)) * 1024 + h * DK + d0 + c4;
    ushort4 v = *(const ushort4*)src;
    tl[r][c4 + 0] = v.x; tl[r][c4 + 1] = v.y; tl[r][c4 + 2] = v.z; tl[r][c4 + 3] = v.w;
    __syncthreads();

    unsigned short* dst = VT + ((size_t)bh * DK + d0 + r) * L_ + l0 + c4;
    ushort4 o;
    o.x = tl[c4 + 0][r]; o.y = tl[c4 + 1][r]; o.z = tl[c4 + 2][r]; o.w = tl[c4 + 3][r];
    *(ushort4*)dst = o;
}

// ---------------------------------------------------------------------------
extern "C" void kernel_launch(void* const* d_in, const int* in_sizes, int n_in,
                              void* d_out, int out_size, void* d_ws, size_t ws_size,
                              hipStream_t stream)
{
    const float* x         = (const float*)d_in[0];
    const float* xx        = (const float*)d_in[1];
    const float* in_proj_w = (const float*)d_in[2];
    const float* conv_w    = (const float*)d_in[3];
    const float* conv_b    = (const float*)d_in[4];
    const float* x_proj_w  = (const float*)d_in[5];
    const float* dt_proj_w = (const float*)d_in[6];
    const float* dt_proj_b = (const float*)d_in[7];
    const float* A_log     = (const float*)d_in[8];
    const float* Dvec      = (const float*)d_in[9];
    const float* wq        = (const float*)d_in[10];
    const float* bq        = (const float*)d_in[11];
    const float* wk        = (const float*)d_in[12];
    const float* bk        = (const float*)d_in[13];
    const float* wv        = (const float*)d_in[14];
    const float* bv        = (const float*)d_in[15];
    const float* wo        = (const float*)d_in[16];
    const float* bo        = (const float*)d_in[17];
    float* out = (float*)d_out;

    char* w = (char*)d_ws;
    const size_t MB = 1024 * 1024, KB = 1024;
    float*          Hc     = (float*)(w + 0);                // 8 MB (scan), dead after scan_c
    float*          delta  = (float*)(w + 16 * MB);          // 16 MB, dead after scan
    unsigned short* Sbuf   = (unsigned short*)(w + 0);       // 32 MB (after scan_c)
    unsigned short* x_bf   = (unsigned short*)(w + 32 * MB); // 8 MB (live thru step 7)
    unsigned short* Q_bf   = (unsigned short*)(w + 40 * MB); // 8 MB -> VT
    unsigned short* VT     = Q_bf;
    unsigned short* y_bf   = (unsigned short*)(w + 48 * MB); // 8 MB -> AO
    unsigned short* AO     = y_bf;
    unsigned short* K_bf   = (unsigned short*)(w + 56 * MB); // 8 MB
    unsigned short* V_bf   = (unsigned short*)(w + 64 * MB); // 8 MB
    unsigned short* u_bf   = (unsigned short*)(w + 72 * MB); // 8 MB (live thru scan_c)
    float*          xdbl   = (float*)(w + 80 * MB);          // 2 MB
    unsigned short* xdblb  = (unsigned short*)(w + 82 * MB); // 1 MB
    unsigned short* w_inT  = (unsigned short*)(w + 83 * MB); // 2 MB (in_proj_w^T bf16)
    unsigned short* w_q    = (unsigned short*)(w + 85 * MB); // 2 MB
    unsigned short* w_k    = (unsigned short*)(w + 87 * MB); // 2 MB
    unsigned short* w_v    = (unsigned short*)(w + 89 * MB); // 2 MB
    unsigned short* w_o    = (unsigned short*)(w + 91 * MB); // 2 MB
    unsigned short* w_xp   = (unsigned short*)(w + 93 * MB);            // 256 KB
    unsigned short* w_dt   = (unsigned short*)(w + 93 * MB + 256 * KB); // 128 KB
    float*          sumdv  = (float*)(w + 93 * MB + 384 * KB);          // 512 KB
    unsigned short* W_qin  = (unsigned short*)(w + 95 * MB); // 2 MB (wq @ W_in, bf16)
    float*          p1     = (float*)(w + 97 * MB);          // 16 MB (split-K partial)

    dim3 blk(256);
    const long long LL = L_;

    // 1. prep: conv+silu (bf16 u only) + x cast + weight casts + in_proj_w^T
    PrepArgs pa;
    pa.xx = xx; pa.cw = conv_w; pa.cb = conv_b; pa.ub = u_bf;
    pa.xs = x; pa.xd = x_bf;
    pa.s[0] = wq;        pa.d[0] = w_q;  pa.n[0] = 1048576; pa.ns[0] = 1048576;
    pa.s[1] = wk;        pa.d[1] = w_k;  pa.n[1] = 1048576; pa.ns[1] = 1048576;
    pa.s[2] = wv;        pa.d[2] = w_v;  pa.n[2] = 1048576; pa.ns[2] = 1048576;
    pa.s[3] = wo;        pa.d[3] = w_o;  pa.n[3] = 1048576; pa.ns[3] = 1048576;
    pa.s[4] = x_proj_w;  pa.d[4] = w_xp; pa.n[4] = 131072;  pa.ns[4] = 98304;
    pa.s[5] = dt_proj_w; pa.d[5] = w_dt; pa.n[5] = 65536;   pa.ns[5] = 65536;
    pa.tsrc = in_proj_w; pa.tdst = w_inT;
    // grid: 16384 conv + 4096 x-cast + 4288 weight + 1024 transpose = 25792
    prep<<<dim3(25792), blk, 0, stream>>>(pa);

    // 2. W_qin = wq @ W_in (weight fold, 1024^3) || x_proj
    {
        GArgs ga = {};
        ga.g[0] = (GDesc){w_q, w_inT, nullptr, nullptr, W_qin,
                          1024, 1024, 1024, 1024, 0, 1, 1.0f, 8, 8};
        ga.g[1] = (GDesc){u_bf, w_xp, nullptr, xdbl, xdblb,
                          1024, 1024, 1024, 128, 128, 2, 1.0f, 1, 32};
        gemm_multi<<<dim3(8, 32, 2), blk, 0, stream>>>(ga);
    }
    // 3. dt_proj (softplus)
    {
        GArgs ga = {};
        ga.g[0] = (GDesc){xdblb, w_dt, dt_proj_b, delta, nullptr,
                          64, 128, 64, 1024, 0, 0 | 4, 1.0f, 8, 32};
        gemm_multi<<<dim3(8, 32, 1), blk, 0, stream>>>(ga);
    }
    // 4-6. chunked scan (u read as bf16; Hc at w+0, freed slot)
    scan_a<<<dim3(512), blk, 0, stream>>>(delta, u_bf, xdbl, A_log, Hc, sumdv);
    scan_b<<<dim3(16), blk, 0, stream>>>(Hc, sumdv, A_log);
    scan_c<<<dim3(512), blk, 0, stream>>>(delta, u_bf, xdbl, A_log, Dvec, Hc, y_bf);

    // 7. Q (folded: x @ W_qin^T + bq) || K || V projections
    {
        GArgs ga = {};
        ga.g[0] = (GDesc){x_bf, W_qin, bq, nullptr, Q_bf, 1024, 1024, 1024, 1024, 0, 1, 1.0f, 8, 32};
        ga.g[1] = (GDesc){y_bf, w_k, bk, nullptr, K_bf, 1024, 1024, 1024, 1024, 0, 1, 1.0f, 8, 32};
        ga.g[2] = (GDesc){y_bf, w_v, bv, nullptr, V_bf, 1024, 1024, 1024, 1024, 0, 1, 1.0f, 8, 32};
        gemm_multi<<<dim3(8, 32, 3), blk, 0, stream>>>(ga);
    }
    // 8. S = Q @ K^T * scale (batched; Sbuf aliases dead scan buffers)
    gemm_batched<<<dim3(8, 8, 16), blk, 0, stream>>>(Q_bf, K_bf, Sbuf,
        DK, 1024, 1024, 1024,
        LL * 1024, 256, LL * 1024, 256,
        4 * LL * 1024, LL * 1024, 0.0625f);
    // 9+10. softmax || V transpose (VT overwrites Q_bf, consumed by step 8)
    softmax_transpose<<<dim3(8192), blk, 0, stream>>>(Sbuf, V_bf, VT);
    // 11. AO = P @ V
    gemm_batched<<<dim3(2, 8, 16), blk, 0, stream>>>(Sbuf, VT, AO,
        1024, 1024, 1024, 1024,
        4 * LL * 1024, LL * 1024,
        4 * (long long)DK * 1024, (long long)DK * 1024,
        LL * 1024, 256, 1.0f);
    // 12. out = AO @ wo^T + bo — split-K x2 (512 blocks = 2/CU) + reduce
    {
        GArgs ga = {};
        ga.g[0] = (GDesc){AO, w_o, nullptr, out, nullptr,
                          512, 1024, 1024, 1024, 0, 0, 1.0f, 8, 32};
        ga.g[1] = (GDesc){AO + 512, w_o + 512, nullptr, p1, nullptr,
                          512, 1024, 1024, 1024, 0, 0, 1.0f, 8, 32};
        gemm_multi<<<dim3(8, 32, 2), blk, 0, stream>>>(ga);
    }
    addout<<<dim3(4096), blk, 0, stream>>>(out, p1, bo);
}

// Round 12
// 392.163 us; speedup vs baseline: 1.0175x; 1.0175x over previous
//
#include <hip/hip_runtime.h>
#include <math.h>

#define B_  4
#define L_  1024
#define DM  1024
#define DI  1024
#define DS  16
#define DR  64
#define DCV 4
#define NH  4
#define DK  256

#define NCH 32         // scan time-chunks
#define CHL (L_ / NCH) // 32 steps per chunk

typedef __attribute__((ext_vector_type(8))) short short8;
typedef __attribute__((ext_vector_type(4))) float floatx4;

static __device__ __forceinline__ unsigned short f2bf(float f) {
    unsigned int u = __float_as_uint(f);
    u += 0x7fffu + ((u >> 16) & 1u);
    return (unsigned short)(u >> 16);
}
static __device__ __forceinline__ float bf2f(unsigned short s) {
    return __uint_as_float(((unsigned int)s) << 16);
}

#define GLL(gp, lp) __builtin_amdgcn_global_load_lds( \
        (const __attribute__((address_space(1))) void*)(gp), \
        (__attribute__((address_space(3))) void*)(lp), 16, 0, 0)

// XCD-aware rectangular tile remap (T1). Bijective when 2|gx and 4|gy.
static __device__ __forceinline__ void xcd_rect(int gx, int gy, int& tx, int& ty)
{
    int n = blockIdx.x + gx * blockIdx.y;
    if ((gx & 1) == 0 && (gy & 3) == 0) {
        int xcd = n & 7, j = n >> 3;
        int hx = gx >> 1, qy = gy >> 2;
        tx = (xcd & 1) * hx + (j % hx);
        ty = (xcd >> 1) * qy + (j / hx);
    } else {
        tx = blockIdx.x; ty = blockIdx.y;
    }
}

// ---------------------------------------------------------------------------
// prep: fused conv+silu (region 0, scalar; bf16-only u output), x cast,
// 6 row-major weight casts, and a transposed bf16 cast of in_proj_w (for
// the Q-weight fold: Q = x @ (wq @ W_in)^T -> combo GEMM needs W_in^T).
// Regions: [0,16384) conv | [ ,+4096) x cast | 6 weights | [ ,+1024) transpose
// ---------------------------------------------------------------------------
struct PrepArgs {
    const float* xx; const float* cw; const float* cb;
    unsigned short* ub;
    const float* xs; unsigned short* xd;
    const float* s[6]; unsigned short* d[6];
    int n[6];   // dest elements (mult of 1024)
    int ns[6];  // source elements (<= n, zero-pad past)
    const float* tsrc; unsigned short* tdst;  // in_proj_w -> bf16 transposed
};

__global__ __launch_bounds__(256) void prep(PrepArgs pa)
{
    __shared__ unsigned short tl[32][36];
    int bid = blockIdx.x, tid = threadIdx.x;
    if (bid < 16384) {
        // conv + silu (scalar, 1 elem/thread); u stored bf16 only
        int idx = bid * 256 + tid;
        int d = idx & (DI - 1);
        int l = (idx >> 10) & (L_ - 1);
        int b = idx >> 20;
        const float* xb = pa.xx + (size_t)b * L_ * DI + d;
        float z = pa.cb[d];
#pragma unroll
        for (int j = 0; j < DCV; j++) {
            int t = l - (DCV - 1) + j;
            if (t >= 0) z += xb[(size_t)t * DI] * pa.cw[d * DCV + j];
        }
        float v = z / (1.0f + __expf(-z));
        pa.ub[idx] = f2bf(v);
        return;
    }
    bid -= 16384;
    if (bid < 4096) {
        int i = (bid * 256 + tid) * 4;
        float4 v = *(const float4*)(pa.xs + i);
        ushort4 o;
        o.x = f2bf(v.x); o.y = f2bf(v.y); o.z = f2bf(v.z); o.w = f2bf(v.w);
        *(ushort4*)(pa.xd + i) = o;
        return;
    }
    bid -= 4096;
#pragma unroll
    for (int r = 0; r < 6; r++) {
        int nb = pa.n[r] >> 10;
        if (bid < nb) {
            int i = (bid * 256 + tid) * 4;
            int ns = pa.ns[r];
            const float* s = pa.s[r];
            ushort4 o;
            if (i + 4 <= ns) {
                float4 v = *(const float4*)(s + i);
                o.x = f2bf(v.x); o.y = f2bf(v.y); o.z = f2bf(v.z); o.w = f2bf(v.w);
            } else {
                float v[4];
#pragma unroll
                for (int j = 0; j < 4; j++) v[j] = (i + j < ns) ? s[i + j] : 0.f;
                o.x = f2bf(v[0]); o.y = f2bf(v[1]); o.z = f2bf(v[2]); o.w = f2bf(v[3]);
            }
            *(ushort4*)(pa.d[r] + i) = o;
            return;
        }
        bid -= nb;
    }
    // transposed cast region: bid in [0,1024), one 32x32 tile per block
    // tdst[n][j] = tsrc[j][n], bf16
    int j0 = (bid >> 5) * 32;
    int n0 = (bid & 31) * 32;
    int r = tid >> 3, c4 = (tid & 7) * 4;
    float4 v = *(const float4*)(pa.tsrc + (size_t)(j0 + r) * 1024 + n0 + c4);
    tl[r][c4 + 0] = f2bf(v.x); tl[r][c4 + 1] = f2bf(v.y);
    tl[r][c4 + 2] = f2bf(v.z); tl[r][c4 + 3] = f2bf(v.w);
    __syncthreads();
    ushort4 o;
    o.x = tl[c4 + 0][r]; o.y = tl[c4 + 1][r];
    o.z = tl[c4 + 2][r]; o.w = tl[c4 + 3][r];
    *(ushort4*)(pa.tdst + (size_t)(n0 + r) * 1024 + j0 + c4) = o;
}

// ---------------------------------------------------------------------------
// Multi-descriptor bf16 MFMA GEMM: per z, C = act(A @ W^T * scale + bias)
// mode & 3: 0 = fp32 out, 1 = bf16 out, 2 = both. mode & 4: softplus.
// R3-proven: 3-stage pipeline, counted vmcnt (T3/T4) + LDS chunk-XOR
// swizzle (T2, conflicts measured 0) + setprio (T5) + XCD rect remap (T1).
// ---------------------------------------------------------------------------
struct GDesc {
    const unsigned short* A;
    const unsigned short* W;
    const float* bias;
    float* Cf;
    unsigned short* Cb;
    int K, lda, ldw, ldc, ldc2;
    int mode;
    float scale;
    int gx, gy;
};
struct GArgs { GDesc g[3]; };

__global__ __launch_bounds__(256) void gemm_multi(GArgs ga)
{
    GDesc g = ga.g[blockIdx.z];
    int bx, by;
    xcd_rect(gridDim.x, gridDim.y, bx, by);
    if (bx >= g.gx || by >= g.gy) return;

    __shared__ __align__(16) unsigned short Asm[3][128 * 32];
    __shared__ __align__(16) unsigned short Bsm[3][128 * 32];

    int tid = threadIdx.x;
    int wid = tid >> 6;
    int lane = tid & 63;
    int wm = wid & 1, wn = wid >> 1;
    int lr = lane & 15, quad = lane >> 4;
    int sq = quad ^ ((lr >> 1) & 3);   // swizzled 16B-chunk index for reads

    const unsigned short* Ab = g.A + (size_t)by * 128 * g.lda;
    const unsigned short* Wb = g.W + (size_t)bx * 128 * g.ldw;

    int srow = tid >> 2;
    int scol = ((tid & 3) ^ ((tid >> 3) & 3)) * 8;  // pre-swizzled global chunk
    const unsigned short* Ap = Ab + (size_t)srow * g.lda + scol;
    const unsigned short* Wp = Wb + (size_t)srow * g.ldw + scol;

    int lbase = (wid * 16) * 32;

    floatx4 acc[4][4];
#pragma unroll
    for (int i = 0; i < 4; i++)
#pragma unroll
        for (int j = 0; j < 4; j++) acc[i][j] = (floatx4){0.f, 0.f, 0.f, 0.f};

#define STAGE_M(buf) do { \
        GLL(Ap, &Asm[buf][lbase]); \
        GLL(Ap + (size_t)64 * g.lda, &Asm[buf][lbase + 64 * 32]); \
        GLL(Wp, &Bsm[buf][lbase]); \
        GLL(Wp + (size_t)64 * g.ldw, &Bsm[buf][lbase + 64 * 32]); \
        Ap += 32; Wp += 32; \
    } while (0)

    int nK = g.K >> 5;
    STAGE_M(0);
    if (nK > 1) STAGE_M(1);

    int cur = 0, stg = 2;
    for (int k = 0; k < nK - 1; k++) {
        asm volatile("s_waitcnt vmcnt(4)" ::: "memory");
        __builtin_amdgcn_s_barrier();
        __builtin_amdgcn_sched_barrier(0);

        short8 af[4], bf[4];
#pragma unroll
        for (int mt = 0; mt < 4; mt++)
            af[mt] = *(const short8*)&Asm[cur][(wm * 64 + mt * 16 + lr) * 32 + sq * 8];
#pragma unroll
        for (int nt = 0; nt < 4; nt++)
            bf[nt] = *(const short8*)&Bsm[cur][(wn * 64 + nt * 16 + lr) * 32 + sq * 8];

        if (k + 2 < nK) {
            STAGE_M(stg);
            stg = (stg == 2) ? 0 : stg + 1;
        }

        __builtin_amdgcn_s_setprio(1);
#pragma unroll
        for (int mt = 0; mt < 4; mt++)
#pragma unroll
            for (int nt = 0; nt < 4; nt++)
                acc[mt][nt] = __builtin_amdgcn_mfma_f32_16x16x32_bf16(
                    af[mt], bf[nt], acc[mt][nt], 0, 0, 0);
        __builtin_amdgcn_s_setprio(0);
        cur = (cur == 2) ? 0 : cur + 1;
    }
    {
        asm volatile("s_waitcnt vmcnt(0)" ::: "memory");
        __builtin_amdgcn_s_barrier();
        __builtin_amdgcn_sched_barrier(0);

        short8 af[4], bf[4];
#pragma unroll
        for (int mt = 0; mt < 4; mt++)
            af[mt] = *(const short8*)&Asm[cur][(wm * 64 + mt * 16 + lr) * 32 + sq * 8];
#pragma unroll
        for (int nt = 0; nt < 4; nt++)
            bf[nt] = *(const short8*)&Bsm[cur][(wn * 64 + nt * 16 + lr) * 32 + sq * 8];
        __builtin_amdgcn_s_setprio(1);
#pragma unroll
        for (int mt = 0; mt < 4; mt++)
#pragma unroll
            for (int nt = 0; nt < 4; nt++)
                acc[mt][nt] = __builtin_amdgcn_mfma_f32_16x16x32_bf16(
                    af[mt], bf[nt], acc[mt][nt], 0, 0, 0);
        __builtin_amdgcn_s_setprio(0);
    }
#undef STAGE_M

    int bm = by * 128, bn = bx * 128;
    int m = g.mode & 3;
#pragma unroll
    for (int mt = 0; mt < 4; mt++) {
#pragma unroll
        for (int nt = 0; nt < 4; nt++) {
            int row0 = bm + wm * 64 + mt * 16 + quad * 4;
            int col = bn + wn * 64 + nt * 16 + lr;
            float bv = g.bias ? g.bias[col] : 0.f;
#pragma unroll
            for (int i = 0; i < 4; i++) {
                float v = acc[mt][nt][i] * g.scale + bv;
                if (g.mode & 4) v = (v > 15.f) ? v : log1pf(__expf(v));
                if (m == 0) {
                    g.Cf[(size_t)(row0 + i) * g.ldc + col] = v;
                } else if (m == 1) {
                    g.Cb[(size_t)(row0 + i) * g.ldc + col] = f2bf(v);
                } else {
                    g.Cf[(size_t)(row0 + i) * g.ldc + col] = v;
                    g.Cb[(size_t)(row0 + i) * g.ldc2 + col] = f2bf(v);
                }
            }
        }
    }
}

// ---------------------------------------------------------------------------
// Batched-strided bf16 MFMA GEMM (attention): z -> b=z>>2, h=z&3
// Same 3-stage counted-vmcnt + swizzle + setprio K-loop, + XCD rect remap.
// ---------------------------------------------------------------------------
__global__ __launch_bounds__(256) void gemm_batched(
    const unsigned short* __restrict__ A, const unsigned short* __restrict__ W,
    unsigned short* __restrict__ C,
    int K, int lda, int ldw, int ldc,
    long long sA1, long long sA2, long long sW1, long long sW2,
    long long sC1, long long sC2, float scale)
{
    __shared__ __align__(16) unsigned short Asm[3][128 * 32];
    __shared__ __align__(16) unsigned short Bsm[3][128 * 32];

    int bx, by;
    xcd_rect(gridDim.x, gridDim.y, bx, by);

    int z = blockIdx.z;
    long long bq = z >> 2, hq = z & 3;
    int tid = threadIdx.x;
    int wid = tid >> 6;
    int lane = tid & 63;
    int wm = wid & 1, wn = wid >> 1;
    int lr = lane & 15, quad = lane >> 4;
    int sq = quad ^ ((lr >> 1) & 3);

    const unsigned short* Ab = A + bq * sA1 + hq * sA2 + (size_t)by * 128 * lda;
    const unsigned short* Wb = W + bq * sW1 + hq * sW2 + (size_t)bx * 128 * ldw;

    int srow = tid >> 2;
    int scol = ((tid & 3) ^ ((tid >> 3) & 3)) * 8;
    const unsigned short* Ap = Ab + (size_t)srow * lda + scol;
    const unsigned short* Wp = Wb + (size_t)srow * ldw + scol;

    int lbase = (wid * 16) * 32;

    floatx4 acc[4][4];
#pragma unroll
    for (int i = 0; i < 4; i++)
#pragma unroll
        for (int j = 0; j < 4; j++) acc[i][j] = (floatx4){0.f, 0.f, 0.f, 0.f};

#define STAGE_B(buf) do { \
        GLL(Ap, &Asm[buf][lbase]); \
        GLL(Ap + (size_t)64 * lda, &Asm[buf][lbase + 64 * 32]); \
        GLL(Wp, &Bsm[buf][lbase]); \
        GLL(Wp + (size_t)64 * ldw, &Bsm[buf][lbase + 64 * 32]); \
        Ap += 32; Wp += 32; \
    } while (0)

    int nK = K >> 5;
    STAGE_B(0);
    if (nK > 1) STAGE_B(1);

    int cur = 0, stg = 2;
    for (int k = 0; k < nK - 1; k++) {
        asm volatile("s_waitcnt vmcnt(4)" ::: "memory");
        __builtin_amdgcn_s_barrier();
        __builtin_amdgcn_sched_barrier(0);

        short8 af[4], bf[4];
#pragma unroll
        for (int mt = 0; mt < 4; mt++)
            af[mt] = *(const short8*)&Asm[cur][(wm * 64 + mt * 16 + lr) * 32 + sq * 8];
#pragma unroll
        for (int nt = 0; nt < 4; nt++)
            bf[nt] = *(const short8*)&Bsm[cur][(wn * 64 + nt * 16 + lr) * 32 + sq * 8];

        if (k + 2 < nK) {
            STAGE_B(stg);
            stg = (stg == 2) ? 0 : stg + 1;
        }

        __builtin_amdgcn_s_setprio(1);
#pragma unroll
        for (int mt = 0; mt < 4; mt++)
#pragma unroll
            for (int nt = 0; nt < 4; nt++)
                acc[mt][nt] = __builtin_amdgcn_mfma_f32_16x16x32_bf16(
                    af[mt], bf[nt], acc[mt][nt], 0, 0, 0);
        __builtin_amdgcn_s_setprio(0);
        cur = (cur == 2) ? 0 : cur + 1;
    }
    {
        asm volatile("s_waitcnt vmcnt(0)" ::: "memory");
        __builtin_amdgcn_s_barrier();
        __builtin_amdgcn_sched_barrier(0);

        short8 af[4], bf[4];
#pragma unroll
        for (int mt = 0; mt < 4; mt++)
            af[mt] = *(const short8*)&Asm[cur][(wm * 64 + mt * 16 + lr) * 32 + sq * 8];
#pragma unroll
        for (int nt = 0; nt < 4; nt++)
            bf[nt] = *(const short8*)&Bsm[cur][(wn * 64 + nt * 16 + lr) * 32 + sq * 8];
        __builtin_amdgcn_s_setprio(1);
#pragma unroll
        for (int mt = 0; mt < 4; mt++)
#pragma unroll
            for (int nt = 0; nt < 4; nt++)
                acc[mt][nt] = __builtin_amdgcn_mfma_f32_16x16x32_bf16(
                    af[mt], bf[nt], acc[mt][nt], 0, 0, 0);
        __builtin_amdgcn_s_setprio(0);
    }
#undef STAGE_B

    long long coff = bq * sC1 + hq * sC2;
    int bm = by * 128, bn = bx * 128;
    unsigned short* Cb = C + coff;

#pragma unroll
    for (int mt = 0; mt < 4; mt++) {
#pragma unroll
        for (int nt = 0; nt < 4; nt++) {
            int row0 = bm + wm * 64 + mt * 16 + quad * 4;
            int col = bn + wn * 64 + nt * 16 + lr;
#pragma unroll
            for (int i = 0; i < 4; i++)
                Cb[(size_t)(row0 + i) * ldc + col] = f2bf(acc[mt][nt][i] * scale);
        }
    }
}

// ---------------------------------------------------------------------------
// Scan phase A: one thread = (b,d,chunk), 16 states in registers.
// u is read as bf16 (single stored copy).
// ---------------------------------------------------------------------------
__global__ __launch_bounds__(256) void scan_a(
    const float* __restrict__ delta, const unsigned short* __restrict__ u,
    const float* __restrict__ xdbl, const float* __restrict__ A_log,
    float* __restrict__ Hc, float* __restrict__ sumdv)
{
    int gid = blockIdx.x * 256 + threadIdx.x;
    int c = gid >> 12;
    int bd = gid & 4095;
    int b = bd >> 10, d = bd & 1023;

    float a[16];
#pragma unroll
    for (int j = 0; j < 4; j++) {
        float4 al = *(const float4*)(A_log + d * 16 + j * 4);
        a[j * 4 + 0] = -__expf(al.x); a[j * 4 + 1] = -__expf(al.y);
        a[j * 4 + 2] = -__expf(al.z); a[j * 4 + 3] = -__expf(al.w);
    }
    float h[16];
#pragma unroll
    for (int n = 0; n < 16; n++) h[n] = 0.f;
    float sd = 0.f;

    int t0 = c * CHL;
    const float* dp = delta + ((size_t)(b * L_) + t0) * DI + d;
    const unsigned short* up = u + ((size_t)(b * L_) + t0) * DI + d;
    const float* xp = xdbl + ((size_t)(b * L_) + t0) * 128;

#pragma unroll 4
    for (int t = 0; t < CHL; t++) {
        float dv = dp[t * DI];
        float uv = bf2f(up[t * DI]);
        float duv = dv * uv;
        sd += dv;
        float Bv[16];
#pragma unroll
        for (int j = 0; j < 4; j++) {
            float4 bq = *(const float4*)(xp + t * 128 + 64 + j * 4);
            Bv[j * 4 + 0] = bq.x; Bv[j * 4 + 1] = bq.y;
            Bv[j * 4 + 2] = bq.z; Bv[j * 4 + 3] = bq.w;
        }
#pragma unroll
        for (int n = 0; n < 16; n++)
            h[n] = __expf(dv * a[n]) * h[n] + duv * Bv[n];
    }

    float* hp = Hc + ((size_t)c * 4096 + bd) * 16;
#pragma unroll
    for (int j = 0; j < 4; j++)
        *(float4*)(hp + j * 4) = make_float4(h[j * 4], h[j * 4 + 1], h[j * 4 + 2], h[j * 4 + 3]);
    sumdv[c * 4096 + bd] = sd;
}

// ---------------------------------------------------------------------------
// Scan phase B: in-place combine — Hc[c][bd][*] becomes chunk START state
// ---------------------------------------------------------------------------
__global__ __launch_bounds__(256) void scan_b(
    float* __restrict__ Hc, const float* __restrict__ sumdv,
    const float* __restrict__ A_log)
{
    int bd = blockIdx.x * 256 + threadIdx.x;
    int d = bd & 1023;

    float a[16];
#pragma unroll
    for (int j = 0; j < 4; j++) {
        float4 al = *(const float4*)(A_log + d * 16 + j * 4);
        a[j * 4 + 0] = -__expf(al.x); a[j * 4 + 1] = -__expf(al.y);
        a[j * 4 + 2] = -__expf(al.z); a[j * 4 + 3] = -__expf(al.w);
    }
    float H[16];
#pragma unroll
    for (int n = 0; n < 16; n++) H[n] = 0.f;

    for (int c = 0; c < NCH; c++) {
        float* hp = Hc + ((size_t)c * 4096 + bd) * 16;
        float sdv = sumdv[c * 4096 + bd];
        float hc[16];
#pragma unroll
        for (int j = 0; j < 4; j++) {
            float4 q = *(const float4*)(hp + j * 4);
            hc[j * 4 + 0] = q.x; hc[j * 4 + 1] = q.y; hc[j * 4 + 2] = q.z; hc[j * 4 + 3] = q.w;
        }
#pragma unroll
        for (int j = 0; j < 4; j++)
            *(float4*)(hp + j * 4) = make_float4(H[j * 4], H[j * 4 + 1], H[j * 4 + 2], H[j * 4 + 3]);
#pragma unroll
        for (int n = 0; n < 16; n++)
            H[n] = __expf(a[n] * sdv) * H[n] + hc[n];
    }
}

// ---------------------------------------------------------------------------
// Scan phase C: re-run chunk from start state, emit y (bf16). u read bf16.
// ---------------------------------------------------------------------------
__global__ __launch_bounds__(256) void scan_c(
    const float* __restrict__ delta, const unsigned short* __restrict__ u,
    const float* __restrict__ xdbl, const float* __restrict__ A_log,
    const float* __restrict__ Dv, const float* __restrict__ Hstart,
    unsigned short* __restrict__ y)
{
    int gid = blockIdx.x * 256 + threadIdx.x;
    int c = gid >> 12;
    int bd = gid & 4095;
    int b = bd >> 10, d = bd & 1023;

    float a[16];
#pragma unroll
    for (int j = 0; j < 4; j++) {
        float4 al = *(const float4*)(A_log + d * 16 + j * 4);
        a[j * 4 + 0] = -__expf(al.x); a[j * 4 + 1] = -__expf(al.y);
        a[j * 4 + 2] = -__expf(al.z); a[j * 4 + 3] = -__expf(al.w);
    }
    float h[16];
    const float* hp = Hstart + ((size_t)c * 4096 + bd) * 16;
#pragma unroll
    for (int j = 0; j < 4; j++) {
        float4 q = *(const float4*)(hp + j * 4);
        h[j * 4 + 0] = q.x; h[j * 4 + 1] = q.y; h[j * 4 + 2] = q.z; h[j * 4 + 3] = q.w;
    }
    float Dd = Dv[d];

    int t0 = c * CHL;
    const float* dp = delta + ((size_t)(b * L_) + t0) * DI + d;
    const unsigned short* up = u + ((size_t)(b * L_) + t0) * DI + d;
    const float* xp = xdbl + ((size_t)(b * L_) + t0) * 128;
    unsigned short* yp = y + ((size_t)(b * L_) + t0) * DI + d;

#pragma unroll 4
    for (int t = 0; t < CHL; t++) {
        float dv = dp[t * DI];
        float uv = bf2f(up[t * DI]);
        float duv = dv * uv;
        float Bv[16], Cv[16];
#pragma unroll
        for (int j = 0; j < 4; j++) {
            float4 bq = *(const float4*)(xp + t * 128 + 64 + j * 4);
            Bv[j * 4 + 0] = bq.x; Bv[j * 4 + 1] = bq.y;
            Bv[j * 4 + 2] = bq.z; Bv[j * 4 + 3] = bq.w;
            float4 cq = *(const float4*)(xp + t * 128 + 80 + j * 4);
            Cv[j * 4 + 0] = cq.x; Cv[j * 4 + 1] = cq.y;
            Cv[j * 4 + 2] = cq.z; Cv[j * 4 + 3] = cq.w;
        }
        float ys = 0.f;
#pragma unroll
        for (int n = 0; n < 16; n++) {
            h[n] = __expf(dv * a[n]) * h[n] + duv * Bv[n];
            ys += h[n] * Cv[n];
        }
        yp[t * DI] = f2bf(ys + uv * Dd);
    }
}

// ---------------------------------------------------------------------------
// Merged: row softmax over S (blocks 0..4095) + V->VT transpose
// (blocks 4096..8191). Independent work, one dispatch.
// ---------------------------------------------------------------------------
__global__ __launch_bounds__(256) void softmax_transpose(
    unsigned short* __restrict__ S,
    const unsigned short* __restrict__ V, unsigned short* __restrict__ VT)
{
    __shared__ unsigned short tl[32][36];
    int bid = blockIdx.x;
    if (bid < 4096) {
        int row = bid * 4 + (threadIdx.x >> 6);
        int lane = threadIdx.x & 63;
        unsigned short* p = S + (size_t)row * 1024;

        float v[16];
#pragma unroll
        for (int ch = 0; ch < 4; ch++) {
            ushort4 u4 = *(const ushort4*)(p + ch * 256 + lane * 4);
            v[ch * 4 + 0] = bf2f(u4.x); v[ch * 4 + 1] = bf2f(u4.y);
            v[ch * 4 + 2] = bf2f(u4.z); v[ch * 4 + 3] = bf2f(u4.w);
        }
        float m = -1e30f;
#pragma unroll
        for (int i = 0; i < 16; i++) m = fmaxf(m, v[i]);
#pragma unroll
        for (int off = 32; off >= 1; off >>= 1) m = fmaxf(m, __shfl_xor(m, off));
        float s = 0.f;
#pragma unroll
        for (int i = 0; i < 16; i++) { v[i] = __expf(v[i] - m); s += v[i]; }
#pragma unroll
        for (int off = 32; off >= 1; off >>= 1) s += __shfl_xor(s, off);
        float inv = 1.0f / s;
#pragma unroll
        for (int ch = 0; ch < 4; ch++) {
            ushort4 o;
            o.x = f2bf(v[ch * 4 + 0] * inv); o.y = f2bf(v[ch * 4 + 1] * inv);
            o.z = f2bf(v[ch * 4 + 2] * inv); o.w = f2bf(v[ch * 4 + 3] * inv);
            *(ushort4*)(p + ch * 256 + lane * 4) = o;
        }
        return;
    }
    int tb = bid - 4096;
    int bh = tb >> 8;
    int rem = tb & 255;
    int d0 = (rem >> 5) * 32;
    int l0 = (rem & 31) * 32;
    int b = bh >> 2, h = bh & 3;
    int tid = threadIdx.x;
    int r = tid >> 3, c4 = (tid & 7) * 4;

    const unsigned short* src = V + ((size_t)(b * L_ + l0 + r)) * 1024 + h * DK + d0 + c4;
    ushort4 v = *(const ushort4*)src;
    tl[r][c4 + 0] = v.x; tl[r][c4 + 1] = v.y; tl[r][c4 + 2] = v.z; tl[r][c4 + 3] = v.w;
    __syncthreads();

    unsigned short* dst = VT + ((size_t)bh * DK + d0 + r) * L_ + l0 + c4;
    ushort4 o;
    o.x = tl[c4 + 0][r]; o.y = tl[c4 + 1][r]; o.z = tl[c4 + 2][r]; o.w = tl[c4 + 3][r];
    *(ushort4*)dst = o;
}

// ---------------------------------------------------------------------------
extern "C" void kernel_launch(void* const* d_in, const int* in_sizes, int n_in,
                              void* d_out, int out_size, void* d_ws, size_t ws_size,
                              hipStream_t stream)
{
    const float* x         = (const float*)d_in[0];
    const float* xx        = (const float*)d_in[1];
    const float* in_proj_w = (const float*)d_in[2];
    const float* conv_w    = (const float*)d_in[3];
    const float* conv_b    = (const float*)d_in[4];
    const float* x_proj_w  = (const float*)d_in[5];
    const float* dt_proj_w = (const float*)d_in[6];
    const float* dt_proj_b = (const float*)d_in[7];
    const float* A_log     = (const float*)d_in[8];
    const float* Dvec      = (const float*)d_in[9];
    const float* wq        = (const float*)d_in[10];
    const float* bq        = (const float*)d_in[11];
    const float* wk        = (const float*)d_in[12];
    const float* bk        = (const float*)d_in[13];
    const float* wv        = (const float*)d_in[14];
    const float* bv        = (const float*)d_in[15];
    const float* wo        = (const float*)d_in[16];
    const float* bo        = (const float*)d_in[17];
    float* out = (float*)d_out;

    char* w = (char*)d_ws;
    const size_t MB = 1024 * 1024, KB = 1024;
    float*          Hc     = (float*)(w + 0);                // 8 MB (scan), dead after scan_c
    float*          delta  = (float*)(w + 16 * MB);          // 16 MB, dead after scan
    unsigned short* Sbuf   = (unsigned short*)(w + 0);       // 32 MB (after scan_c)
    unsigned short* x_bf   = (unsigned short*)(w + 32 * MB); // 8 MB (live thru step 7)
    unsigned short* Q_bf   = (unsigned short*)(w + 40 * MB); // 8 MB -> VT
    unsigned short* VT     = Q_bf;
    unsigned short* y_bf   = (unsigned short*)(w + 48 * MB); // 8 MB -> AO
    unsigned short* AO     = y_bf;
    unsigned short* K_bf   = (unsigned short*)(w + 56 * MB); // 8 MB
    unsigned short* V_bf   = (unsigned short*)(w + 64 * MB); // 8 MB
    unsigned short* u_bf   = (unsigned short*)(w + 72 * MB); // 8 MB (live thru scan_c)
    float*          xdbl   = (float*)(w + 80 * MB);          // 2 MB
    unsigned short* xdblb  = (unsigned short*)(w + 82 * MB); // 1 MB
    unsigned short* w_inT  = (unsigned short*)(w + 83 * MB); // 2 MB (in_proj_w^T bf16)
    unsigned short* w_q    = (unsigned short*)(w + 85 * MB); // 2 MB
    unsigned short* w_k    = (unsigned short*)(w + 87 * MB); // 2 MB
    unsigned short* w_v    = (unsigned short*)(w + 89 * MB); // 2 MB
    unsigned short* w_o    = (unsigned short*)(w + 91 * MB); // 2 MB
    unsigned short* w_xp   = (unsigned short*)(w + 93 * MB);            // 256 KB
    unsigned short* w_dt   = (unsigned short*)(w + 93 * MB + 256 * KB); // 128 KB
    float*          sumdv  = (float*)(w + 93 * MB + 384 * KB);          // 512 KB
    unsigned short* W_qin  = (unsigned short*)(w + 95 * MB); // 2 MB (wq @ W_in, bf16)

    dim3 blk(256);
    const long long LL = L_;

    // 1. prep: conv+silu (bf16 u only) + x cast + weight casts + in_proj_w^T
    PrepArgs pa;
    pa.xx = xx; pa.cw = conv_w; pa.cb = conv_b; pa.ub = u_bf;
    pa.xs = x; pa.xd = x_bf;
    pa.s[0] = wq;        pa.d[0] = w_q;  pa.n[0] = 1048576; pa.ns[0] = 1048576;
    pa.s[1] = wk;        pa.d[1] = w_k;  pa.n[1] = 1048576; pa.ns[1] = 1048576;
    pa.s[2] = wv;        pa.d[2] = w_v;  pa.n[2] = 1048576; pa.ns[2] = 1048576;
    pa.s[3] = wo;        pa.d[3] = w_o;  pa.n[3] = 1048576; pa.ns[3] = 1048576;
    pa.s[4] = x_proj_w;  pa.d[4] = w_xp; pa.n[4] = 131072;  pa.ns[4] = 98304;
    pa.s[5] = dt_proj_w; pa.d[5] = w_dt; pa.n[5] = 65536;   pa.ns[5] = 65536;
    pa.tsrc = in_proj_w; pa.tdst = w_inT;
    // grid: 16384 conv + 4096 x-cast + 4288 weight + 1024 transpose = 25792
    prep<<<dim3(25792), blk, 0, stream>>>(pa);

    // 2. W_qin = wq @ W_in (weight fold, 1024^3) || x_proj
    {
        GArgs ga = {};
        ga.g[0] = (GDesc){w_q, w_inT, nullptr, nullptr, W_qin,
                          1024, 1024, 1024, 1024, 0, 1, 1.0f, 8, 8};
        ga.g[1] = (GDesc){u_bf, w_xp, nullptr, xdbl, xdblb,
                          1024, 1024, 1024, 128, 128, 2, 1.0f, 1, 32};
        gemm_multi<<<dim3(8, 32, 2), blk, 0, stream>>>(ga);
    }
    // 3. dt_proj (softplus)
    {
        GArgs ga = {};
        ga.g[0] = (GDesc){xdblb, w_dt, dt_proj_b, delta, nullptr,
                          64, 128, 64, 1024, 0, 0 | 4, 1.0f, 8, 32};
        gemm_multi<<<dim3(8, 32, 1), blk, 0, stream>>>(ga);
    }
    // 4-6. chunked scan (u read as bf16; Hc at w+0, freed slot)
    scan_a<<<dim3(512), blk, 0, stream>>>(delta, u_bf, xdbl, A_log, Hc, sumdv);
    scan_b<<<dim3(16), blk, 0, stream>>>(Hc, sumdv, A_log);
    scan_c<<<dim3(512), blk, 0, stream>>>(delta, u_bf, xdbl, A_log, Dvec, Hc, y_bf);

    // 7. Q (folded: x @ W_qin^T + bq) || K || V projections
    {
        GArgs ga = {};
        ga.g[0] = (GDesc){x_bf, W_qin, bq, nullptr, Q_bf, 1024, 1024, 1024, 1024, 0, 1, 1.0f, 8, 32};
        ga.g[1] = (GDesc){y_bf, w_k, bk, nullptr, K_bf, 1024, 1024, 1024, 1024, 0, 1, 1.0f, 8, 32};
        ga.g[2] = (GDesc){y_bf, w_v, bv, nullptr, V_bf, 1024, 1024, 1024, 1024, 0, 1, 1.0f, 8, 32};
        gemm_multi<<<dim3(8, 32, 3), blk, 0, stream>>>(ga);
    }
    // 8. S = Q @ K^T * scale (batched; Sbuf aliases dead scan buffers)
    gemm_batched<<<dim3(8, 8, 16), blk, 0, stream>>>(Q_bf, K_bf, Sbuf,
        DK, 1024, 1024, 1024,
        LL * 1024, 256, LL * 1024, 256,
        4 * LL * 1024, LL * 1024, 0.0625f);
    // 9+10. softmax || V transpose (VT overwrites Q_bf, consumed by step 8)
    softmax_transpose<<<dim3(8192), blk, 0, stream>>>(Sbuf, V_bf, VT);
    // 11. AO = P @ V
    gemm_batched<<<dim3(2, 8, 16), blk, 0, stream>>>(Sbuf, VT, AO,
        1024, 1024, 1024, 1024,
        4 * LL * 1024, LL * 1024,
        4 * (long long)DK * 1024, (long long)DK * 1024,
        LL * 1024, 256, 1.0f);
    // 12. out = AO @ wo^T + bo (fp32, single dispatch — split-K reverted)
    {
        GArgs ga = {};
        ga.g[0] = (GDesc){AO, w_o, bo, out, nullptr, 1024, 1024, 1024, 1024, 0, 0, 1.0f, 8, 32};
        gemm_multi<<<dim3(8, 32, 1), blk, 0, stream>>>(ga);
    }
}

// Round 13
// 387.484 us; speedup vs baseline: 1.0298x; 1.0121x over previous
//
#include <hip/hip_runtime.h>
#include <math.h>

#define B_  4
#define L_  1024
#define DM  1024
#define DI  1024
#define DS  16
#define DR  64
#define DCV 4
#define NH  4
#define DK  256

#define NCH 32         // scan time-chunks
#define CHL (L_ / NCH) // 32 steps per chunk

typedef __attribute__((ext_vector_type(8))) short short8;
typedef __attribute__((ext_vector_type(4))) float floatx4;

static __device__ __forceinline__ unsigned short f2bf(float f) {
    unsigned int u = __float_as_uint(f);
    u += 0x7fffu + ((u >> 16) & 1u);
    return (unsigned short)(u >> 16);
}
static __device__ __forceinline__ float bf2f(unsigned short s) {
    return __uint_as_float(((unsigned int)s) << 16);
}

#define GLL(gp, lp) __builtin_amdgcn_global_load_lds( \
        (const __attribute__((address_space(1))) void*)(gp), \
        (__attribute__((address_space(3))) void*)(lp), 16, 0, 0)

// XCD-aware rectangular tile remap (T1). Bijective when 2|gx and 4|gy.
static __device__ __forceinline__ void xcd_rect(int gx, int gy, int& tx, int& ty)
{
    int n = blockIdx.x + gx * blockIdx.y;
    if ((gx & 1) == 0 && (gy & 3) == 0) {
        int xcd = n & 7, j = n >> 3;
        int hx = gx >> 1, qy = gy >> 2;
        tx = (xcd & 1) * hx + (j % hx);
        ty = (xcd >> 1) * qy + (j / hx);
    } else {
        tx = blockIdx.x; ty = blockIdx.y;
    }
}

// ---------------------------------------------------------------------------
// prep: fused conv+silu (region 0, scalar; bf16-only u output), x cast,
// 6 row-major weight casts, and a transposed bf16 cast of in_proj_w (for
// the Q-weight fold: Q = x @ (wq @ W_in)^T -> combo GEMM needs W_in^T).
// ---------------------------------------------------------------------------
struct PrepArgs {
    const float* xx; const float* cw; const float* cb;
    unsigned short* ub;
    const float* xs; unsigned short* xd;
    const float* s[6]; unsigned short* d[6];
    int n[6];   // dest elements (mult of 1024)
    int ns[6];  // source elements (<= n, zero-pad past)
    const float* tsrc; unsigned short* tdst;  // in_proj_w -> bf16 transposed
};

__global__ __launch_bounds__(256) void prep(PrepArgs pa)
{
    __shared__ unsigned short tl[32][36];
    int bid = blockIdx.x, tid = threadIdx.x;
    if (bid < 16384) {
        // conv + silu (scalar, 1 elem/thread); u stored bf16 only
        int idx = bid * 256 + tid;
        int d = idx & (DI - 1);
        int l = (idx >> 10) & (L_ - 1);
        int b = idx >> 20;
        const float* xb = pa.xx + (size_t)b * L_ * DI + d;
        float z = pa.cb[d];
#pragma unroll
        for (int j = 0; j < DCV; j++) {
            int t = l - (DCV - 1) + j;
            if (t >= 0) z += xb[(size_t)t * DI] * pa.cw[d * DCV + j];
        }
        float v = z / (1.0f + __expf(-z));
        pa.ub[idx] = f2bf(v);
        return;
    }
    bid -= 16384;
    if (bid < 4096) {
        int i = (bid * 256 + tid) * 4;
        float4 v = *(const float4*)(pa.xs + i);
        ushort4 o;
        o.x = f2bf(v.x); o.y = f2bf(v.y); o.z = f2bf(v.z); o.w = f2bf(v.w);
        *(ushort4*)(pa.xd + i) = o;
        return;
    }
    bid -= 4096;
#pragma unroll
    for (int r = 0; r < 6; r++) {
        int nb = pa.n[r] >> 10;
        if (bid < nb) {
            int i = (bid * 256 + tid) * 4;
            int ns = pa.ns[r];
            const float* s = pa.s[r];
            ushort4 o;
            if (i + 4 <= ns) {
                float4 v = *(const float4*)(s + i);
                o.x = f2bf(v.x); o.y = f2bf(v.y); o.z = f2bf(v.z); o.w = f2bf(v.w);
            } else {
                float v[4];
#pragma unroll
                for (int j = 0; j < 4; j++) v[j] = (i + j < ns) ? s[i + j] : 0.f;
                o.x = f2bf(v[0]); o.y = f2bf(v[1]); o.z = f2bf(v[2]); o.w = f2bf(v[3]);
            }
            *(ushort4*)(pa.d[r] + i) = o;
            return;
        }
        bid -= nb;
    }
    // transposed cast region: bid in [0,1024), one 32x32 tile per block
    int j0 = (bid >> 5) * 32;
    int n0 = (bid & 31) * 32;
    int r = tid >> 3, c4 = (tid & 7) * 4;
    float4 v = *(const float4*)(pa.tsrc + (size_t)(j0 + r) * 1024 + n0 + c4);
    tl[r][c4 + 0] = f2bf(v.x); tl[r][c4 + 1] = f2bf(v.y);
    tl[r][c4 + 2] = f2bf(v.z); tl[r][c4 + 3] = f2bf(v.w);
    __syncthreads();
    ushort4 o;
    o.x = tl[c4 + 0][r]; o.y = tl[c4 + 1][r];
    o.z = tl[c4 + 2][r]; o.w = tl[c4 + 3][r];
    *(ushort4*)(pa.tdst + (size_t)(n0 + r) * 1024 + j0 + c4) = o;
}

// ---------------------------------------------------------------------------
// Shared GEMM descriptor
// ---------------------------------------------------------------------------
struct GDesc {
    const unsigned short* A;
    const unsigned short* W;
    const float* bias;
    float* Cf;
    unsigned short* Cb;
    int K, lda, ldw, ldc, ldc2;
    int mode;
    float scale;
    int gx, gy;
};
struct GArgs { GDesc g[3]; };

// ---------------------------------------------------------------------------
// 128x128-tile multi GEMM (R3-proven). Used where >=3 blocks/CU (steps 7).
// 3-stage pipeline, vmcnt(4) + chunk-XOR swizzle + setprio + XCD rect.
// ---------------------------------------------------------------------------
__global__ __launch_bounds__(256) void gemm_multi(GArgs ga)
{
    GDesc g = ga.g[blockIdx.z];
    int bx, by;
    xcd_rect(gridDim.x, gridDim.y, bx, by);
    if (bx >= g.gx || by >= g.gy) return;

    __shared__ __align__(16) unsigned short Asm[3][128 * 32];
    __shared__ __align__(16) unsigned short Bsm[3][128 * 32];

    int tid = threadIdx.x;
    int wid = tid >> 6;
    int lane = tid & 63;
    int wm = wid & 1, wn = wid >> 1;
    int lr = lane & 15, quad = lane >> 4;
    int sq = quad ^ ((lr >> 1) & 3);

    const unsigned short* Ab = g.A + (size_t)by * 128 * g.lda;
    const unsigned short* Wb = g.W + (size_t)bx * 128 * g.ldw;

    int srow = tid >> 2;
    int scol = ((tid & 3) ^ ((tid >> 3) & 3)) * 8;
    const unsigned short* Ap = Ab + (size_t)srow * g.lda + scol;
    const unsigned short* Wp = Wb + (size_t)srow * g.ldw + scol;

    int lbase = (wid * 16) * 32;

    floatx4 acc[4][4];
#pragma unroll
    for (int i = 0; i < 4; i++)
#pragma unroll
        for (int j = 0; j < 4; j++) acc[i][j] = (floatx4){0.f, 0.f, 0.f, 0.f};

#define STAGE_M(buf) do { \
        GLL(Ap, &Asm[buf][lbase]); \
        GLL(Ap + (size_t)64 * g.lda, &Asm[buf][lbase + 64 * 32]); \
        GLL(Wp, &Bsm[buf][lbase]); \
        GLL(Wp + (size_t)64 * g.ldw, &Bsm[buf][lbase + 64 * 32]); \
        Ap += 32; Wp += 32; \
    } while (0)

    int nK = g.K >> 5;
    STAGE_M(0);
    if (nK > 1) STAGE_M(1);

    int cur = 0, stg = 2;
    for (int k = 0; k < nK - 1; k++) {
        asm volatile("s_waitcnt vmcnt(4)" ::: "memory");
        __builtin_amdgcn_s_barrier();
        __builtin_amdgcn_sched_barrier(0);

        short8 af[4], bf[4];
#pragma unroll
        for (int mt = 0; mt < 4; mt++)
            af[mt] = *(const short8*)&Asm[cur][(wm * 64 + mt * 16 + lr) * 32 + sq * 8];
#pragma unroll
        for (int nt = 0; nt < 4; nt++)
            bf[nt] = *(const short8*)&Bsm[cur][(wn * 64 + nt * 16 + lr) * 32 + sq * 8];

        if (k + 2 < nK) {
            STAGE_M(stg);
            stg = (stg == 2) ? 0 : stg + 1;
        }

        __builtin_amdgcn_s_setprio(1);
#pragma unroll
        for (int mt = 0; mt < 4; mt++)
#pragma unroll
            for (int nt = 0; nt < 4; nt++)
                acc[mt][nt] = __builtin_amdgcn_mfma_f32_16x16x32_bf16(
                    af[mt], bf[nt], acc[mt][nt], 0, 0, 0);
        __builtin_amdgcn_s_setprio(0);
        cur = (cur == 2) ? 0 : cur + 1;
    }
    {
        asm volatile("s_waitcnt vmcnt(0)" ::: "memory");
        __builtin_amdgcn_s_barrier();
        __builtin_amdgcn_sched_barrier(0);

        short8 af[4], bf[4];
#pragma unroll
        for (int mt = 0; mt < 4; mt++)
            af[mt] = *(const short8*)&Asm[cur][(wm * 64 + mt * 16 + lr) * 32 + sq * 8];
#pragma unroll
        for (int nt = 0; nt < 4; nt++)
            bf[nt] = *(const short8*)&Bsm[cur][(wn * 64 + nt * 16 + lr) * 32 + sq * 8];
        __builtin_amdgcn_s_setprio(1);
#pragma unroll
        for (int mt = 0; mt < 4; mt++)
#pragma unroll
            for (int nt = 0; nt < 4; nt++)
                acc[mt][nt] = __builtin_amdgcn_mfma_f32_16x16x32_bf16(
                    af[mt], bf[nt], acc[mt][nt], 0, 0, 0);
        __builtin_amdgcn_s_setprio(0);
    }
#undef STAGE_M

    int bm = by * 128, bn = bx * 128;
    int m = g.mode & 3;
#pragma unroll
    for (int mt = 0; mt < 4; mt++) {
#pragma unroll
        for (int nt = 0; nt < 4; nt++) {
            int row0 = bm + wm * 64 + mt * 16 + quad * 4;
            int col = bn + wn * 64 + nt * 16 + lr;
            float bv = g.bias ? g.bias[col] : 0.f;
#pragma unroll
            for (int i = 0; i < 4; i++) {
                float v = acc[mt][nt][i] * g.scale + bv;
                if (g.mode & 4) v = (v > 15.f) ? v : log1pf(__expf(v));
                if (m == 0) {
                    g.Cf[(size_t)(row0 + i) * g.ldc + col] = v;
                } else if (m == 1) {
                    g.Cb[(size_t)(row0 + i) * g.ldc + col] = f2bf(v);
                } else {
                    g.Cf[(size_t)(row0 + i) * g.ldc + col] = v;
                    g.Cb[(size_t)(row0 + i) * g.ldc2 + col] = f2bf(v);
                }
            }
        }
    }
}

// ---------------------------------------------------------------------------
// 64x128-tile multi GEMM: doubles block count -> 2/CU co-residency for the
// latency-bound low-grid dispatches (fold, x_proj, dt_proj, O-proj).
// Wave grid 2x2, per-wave 32x64 out (acc[2][4]). Stage = 3 GLL/thread
// (A 1, B 2) -> vmcnt(3) steady state. LDS 36 KB. Same swizzle (row-in-tile
// key (lr>>1)&3 is unchanged: wm*32 and mt*16 are 0 mod 4 after >>1).
// ---------------------------------------------------------------------------
__global__ __launch_bounds__(256) void gemm_multi64(GArgs ga)
{
    GDesc g = ga.g[blockIdx.z];
    int bx, by;
    xcd_rect(gridDim.x, gridDim.y, bx, by);
    if (bx >= g.gx || by >= g.gy) return;

    __shared__ __align__(16) unsigned short Asm[3][64 * 32];
    __shared__ __align__(16) unsigned short Bsm[3][128 * 32];

    int tid = threadIdx.x;
    int wid = tid >> 6;
    int lane = tid & 63;
    int wm = wid & 1, wn = wid >> 1;
    int lr = lane & 15, quad = lane >> 4;
    int sq = quad ^ ((lr >> 1) & 3);

    const unsigned short* Ab = g.A + (size_t)by * 64 * g.lda;
    const unsigned short* Wb = g.W + (size_t)bx * 128 * g.ldw;

    int srow = tid >> 2;
    int scol = ((tid & 3) ^ ((tid >> 3) & 3)) * 8;
    const unsigned short* Ap = Ab + (size_t)srow * g.lda + scol;
    const unsigned short* Wp = Wb + (size_t)srow * g.ldw + scol;

    int lbase = (wid * 16) * 32;

    floatx4 acc[2][4];
#pragma unroll
    for (int i = 0; i < 2; i++)
#pragma unroll
        for (int j = 0; j < 4; j++) acc[i][j] = (floatx4){0.f, 0.f, 0.f, 0.f};

#define STAGE_S(buf) do { \
        GLL(Ap, &Asm[buf][lbase]); \
        GLL(Wp, &Bsm[buf][lbase]); \
        GLL(Wp + (size_t)64 * g.ldw, &Bsm[buf][lbase + 64 * 32]); \
        Ap += 32; Wp += 32; \
    } while (0)

    int nK = g.K >> 5;
    STAGE_S(0);
    if (nK > 1) STAGE_S(1);

    int cur = 0, stg = 2;
    for (int k = 0; k < nK - 1; k++) {
        asm volatile("s_waitcnt vmcnt(3)" ::: "memory");
        __builtin_amdgcn_s_barrier();
        __builtin_amdgcn_sched_barrier(0);

        short8 af[2], bf[4];
#pragma unroll
        for (int mt = 0; mt < 2; mt++)
            af[mt] = *(const short8*)&Asm[cur][(wm * 32 + mt * 16 + lr) * 32 + sq * 8];
#pragma unroll
        for (int nt = 0; nt < 4; nt++)
            bf[nt] = *(const short8*)&Bsm[cur][(wn * 64 + nt * 16 + lr) * 32 + sq * 8];

        if (k + 2 < nK) {
            STAGE_S(stg);
            stg = (stg == 2) ? 0 : stg + 1;
        }

        __builtin_amdgcn_s_setprio(1);
#pragma unroll
        for (int mt = 0; mt < 2; mt++)
#pragma unroll
            for (int nt = 0; nt < 4; nt++)
                acc[mt][nt] = __builtin_amdgcn_mfma_f32_16x16x32_bf16(
                    af[mt], bf[nt], acc[mt][nt], 0, 0, 0);
        __builtin_amdgcn_s_setprio(0);
        cur = (cur == 2) ? 0 : cur + 1;
    }
    {
        asm volatile("s_waitcnt vmcnt(0)" ::: "memory");
        __builtin_amdgcn_s_barrier();
        __builtin_amdgcn_sched_barrier(0);

        short8 af[2], bf[4];
#pragma unroll
        for (int mt = 0; mt < 2; mt++)
            af[mt] = *(const short8*)&Asm[cur][(wm * 32 + mt * 16 + lr) * 32 + sq * 8];
#pragma unroll
        for (int nt = 0; nt < 4; nt++)
            bf[nt] = *(const short8*)&Bsm[cur][(wn * 64 + nt * 16 + lr) * 32 + sq * 8];
        __builtin_amdgcn_s_setprio(1);
#pragma unroll
        for (int mt = 0; mt < 2; mt++)
#pragma unroll
            for (int nt = 0; nt < 4; nt++)
                acc[mt][nt] = __builtin_amdgcn_mfma_f32_16x16x32_bf16(
                    af[mt], bf[nt], acc[mt][nt], 0, 0, 0);
        __builtin_amdgcn_s_setprio(0);
    }
#undef STAGE_S

    int bm = by * 64, bn = bx * 128;
    int m = g.mode & 3;
#pragma unroll
    for (int mt = 0; mt < 2; mt++) {
#pragma unroll
        for (int nt = 0; nt < 4; nt++) {
            int row0 = bm + wm * 32 + mt * 16 + quad * 4;
            int col = bn + wn * 64 + nt * 16 + lr;
            float bv = g.bias ? g.bias[col] : 0.f;
#pragma unroll
            for (int i = 0; i < 4; i++) {
                float v = acc[mt][nt][i] * g.scale + bv;
                if (g.mode & 4) v = (v > 15.f) ? v : log1pf(__expf(v));
                if (m == 0) {
                    g.Cf[(size_t)(row0 + i) * g.ldc + col] = v;
                } else if (m == 1) {
                    g.Cb[(size_t)(row0 + i) * g.ldc + col] = f2bf(v);
                } else {
                    g.Cf[(size_t)(row0 + i) * g.ldc + col] = v;
                    g.Cb[(size_t)(row0 + i) * g.ldc2 + col] = f2bf(v);
                }
            }
        }
    }
}

// ---------------------------------------------------------------------------
// Batched-strided bf16 GEMM, 128x128 tile (step 8: QK^T, 4/CU grid).
// ---------------------------------------------------------------------------
__global__ __launch_bounds__(256) void gemm_batched(
    const unsigned short* __restrict__ A, const unsigned short* __restrict__ W,
    unsigned short* __restrict__ C,
    int K, int lda, int ldw, int ldc,
    long long sA1, long long sA2, long long sW1, long long sW2,
    long long sC1, long long sC2, float scale)
{
    __shared__ __align__(16) unsigned short Asm[3][128 * 32];
    __shared__ __align__(16) unsigned short Bsm[3][128 * 32];

    int bx, by;
    xcd_rect(gridDim.x, gridDim.y, bx, by);

    int z = blockIdx.z;
    long long bq = z >> 2, hq = z & 3;
    int tid = threadIdx.x;
    int wid = tid >> 6;
    int lane = tid & 63;
    int wm = wid & 1, wn = wid >> 1;
    int lr = lane & 15, quad = lane >> 4;
    int sq = quad ^ ((lr >> 1) & 3);

    const unsigned short* Ab = A + bq * sA1 + hq * sA2 + (size_t)by * 128 * lda;
    const unsigned short* Wb = W + bq * sW1 + hq * sW2 + (size_t)bx * 128 * ldw;

    int srow = tid >> 2;
    int scol = ((tid & 3) ^ ((tid >> 3) & 3)) * 8;
    const unsigned short* Ap = Ab + (size_t)srow * lda + scol;
    const unsigned short* Wp = Wb + (size_t)srow * ldw + scol;

    int lbase = (wid * 16) * 32;

    floatx4 acc[4][4];
#pragma unroll
    for (int i = 0; i < 4; i++)
#pragma unroll
        for (int j = 0; j < 4; j++) acc[i][j] = (floatx4){0.f, 0.f, 0.f, 0.f};

#define STAGE_B(buf) do { \
        GLL(Ap, &Asm[buf][lbase]); \
        GLL(Ap + (size_t)64 * lda, &Asm[buf][lbase + 64 * 32]); \
        GLL(Wp, &Bsm[buf][lbase]); \
        GLL(Wp + (size_t)64 * ldw, &Bsm[buf][lbase + 64 * 32]); \
        Ap += 32; Wp += 32; \
    } while (0)

    int nK = K >> 5;
    STAGE_B(0);
    if (nK > 1) STAGE_B(1);

    int cur = 0, stg = 2;
    for (int k = 0; k < nK - 1; k++) {
        asm volatile("s_waitcnt vmcnt(4)" ::: "memory");
        __builtin_amdgcn_s_barrier();
        __builtin_amdgcn_sched_barrier(0);

        short8 af[4], bf[4];
#pragma unroll
        for (int mt = 0; mt < 4; mt++)
            af[mt] = *(const short8*)&Asm[cur][(wm * 64 + mt * 16 + lr) * 32 + sq * 8];
#pragma unroll
        for (int nt = 0; nt < 4; nt++)
            bf[nt] = *(const short8*)&Bsm[cur][(wn * 64 + nt * 16 + lr) * 32 + sq * 8];

        if (k + 2 < nK) {
            STAGE_B(stg);
            stg = (stg == 2) ? 0 : stg + 1;
        }

        __builtin_amdgcn_s_setprio(1);
#pragma unroll
        for (int mt = 0; mt < 4; mt++)
#pragma unroll
            for (int nt = 0; nt < 4; nt++)
                acc[mt][nt] = __builtin_amdgcn_mfma_f32_16x16x32_bf16(
                    af[mt], bf[nt], acc[mt][nt], 0, 0, 0);
        __builtin_amdgcn_s_setprio(0);
        cur = (cur == 2) ? 0 : cur + 1;
    }
    {
        asm volatile("s_waitcnt vmcnt(0)" ::: "memory");
        __builtin_amdgcn_s_barrier();
        __builtin_amdgcn_sched_barrier(0);

        short8 af[4], bf[4];
#pragma unroll
        for (int mt = 0; mt < 4; mt++)
            af[mt] = *(const short8*)&Asm[cur][(wm * 64 + mt * 16 + lr) * 32 + sq * 8];
#pragma unroll
        for (int nt = 0; nt < 4; nt++)
            bf[nt] = *(const short8*)&Bsm[cur][(wn * 64 + nt * 16 + lr) * 32 + sq * 8];
        __builtin_amdgcn_s_setprio(1);
#pragma unroll
        for (int mt = 0; mt < 4; mt++)
#pragma unroll
            for (int nt = 0; nt < 4; nt++)
                acc[mt][nt] = __builtin_amdgcn_mfma_f32_16x16x32_bf16(
                    af[mt], bf[nt], acc[mt][nt], 0, 0, 0);
        __builtin_amdgcn_s_setprio(0);
    }
#undef STAGE_B

    long long coff = bq * sC1 + hq * sC2;
    int bm = by * 128, bn = bx * 128;
    unsigned short* Cb = C + coff;

#pragma unroll
    for (int mt = 0; mt < 4; mt++) {
#pragma unroll
        for (int nt = 0; nt < 4; nt++) {
            int row0 = bm + wm * 64 + mt * 16 + quad * 4;
            int col = bn + wn * 64 + nt * 16 + lr;
#pragma unroll
            for (int i = 0; i < 4; i++)
                Cb[(size_t)(row0 + i) * ldc + col] = f2bf(acc[mt][nt][i] * scale);
        }
    }
}

// ---------------------------------------------------------------------------
// Batched-strided bf16 GEMM, 64x128 tile (step 11: PV, 1/CU -> 2/CU).
// Same 3-stage vmcnt(3) pipeline as gemm_multi64.
// ---------------------------------------------------------------------------
__global__ __launch_bounds__(256) void gemm_batched64(
    const unsigned short* __restrict__ A, const unsigned short* __restrict__ W,
    unsigned short* __restrict__ C,
    int K, int lda, int ldw, int ldc,
    long long sA1, long long sA2, long long sW1, long long sW2,
    long long sC1, long long sC2, float scale)
{
    __shared__ __align__(16) unsigned short Asm[3][64 * 32];
    __shared__ __align__(16) unsigned short Bsm[3][128 * 32];

    int bx, by;
    xcd_rect(gridDim.x, gridDim.y, bx, by);

    int z = blockIdx.z;
    long long bq = z >> 2, hq = z & 3;
    int tid = threadIdx.x;
    int wid = tid >> 6;
    int lane = tid & 63;
    int wm = wid & 1, wn = wid >> 1;
    int lr = lane & 15, quad = lane >> 4;
    int sq = quad ^ ((lr >> 1) & 3);

    const unsigned short* Ab = A + bq * sA1 + hq * sA2 + (size_t)by * 64 * lda;
    const unsigned short* Wb = W + bq * sW1 + hq * sW2 + (size_t)bx * 128 * ldw;

    int srow = tid >> 2;
    int scol = ((tid & 3) ^ ((tid >> 3) & 3)) * 8;
    const unsigned short* Ap = Ab + (size_t)srow * lda + scol;
    const unsigned short* Wp = Wb + (size_t)srow * ldw + scol;

    int lbase = (wid * 16) * 32;

    floatx4 acc[2][4];
#pragma unroll
    for (int i = 0; i < 2; i++)
#pragma unroll
        for (int j = 0; j < 4; j++) acc[i][j] = (floatx4){0.f, 0.f, 0.f, 0.f};

#define STAGE_S(buf) do { \
        GLL(Ap, &Asm[buf][lbase]); \
        GLL(Wp, &Bsm[buf][lbase]); \
        GLL(Wp + (size_t)64 * ldw, &Bsm[buf][lbase + 64 * 32]); \
        Ap += 32; Wp += 32; \
    } while (0)

    int nK = K >> 5;
    STAGE_S(0);
    if (nK > 1) STAGE_S(1);

    int cur = 0, stg = 2;
    for (int k = 0; k < nK - 1; k++) {
        asm volatile("s_waitcnt vmcnt(3)" ::: "memory");
        __builtin_amdgcn_s_barrier();
        __builtin_amdgcn_sched_barrier(0);

        short8 af[2], bf[4];
#pragma unroll
        for (int mt = 0; mt < 2; mt++)
            af[mt] = *(const short8*)&Asm[cur][(wm * 32 + mt * 16 + lr) * 32 + sq * 8];
#pragma unroll
        for (int nt = 0; nt < 4; nt++)
            bf[nt] = *(const short8*)&Bsm[cur][(wn * 64 + nt * 16 + lr) * 32 + sq * 8];

        if (k + 2 < nK) {
            STAGE_S(stg);
            stg = (stg == 2) ? 0 : stg + 1;
        }

        __builtin_amdgcn_s_setprio(1);
#pragma unroll
        for (int mt = 0; mt < 2; mt++)
#pragma unroll
            for (int nt = 0; nt < 4; nt++)
                acc[mt][nt] = __builtin_amdgcn_mfma_f32_16x16x32_bf16(
                    af[mt], bf[nt], acc[mt][nt], 0, 0, 0);
        __builtin_amdgcn_s_setprio(0);
        cur = (cur == 2) ? 0 : cur + 1;
    }
    {
        asm volatile("s_waitcnt vmcnt(0)" ::: "memory");
        __builtin_amdgcn_s_barrier();
        __builtin_amdgcn_sched_barrier(0);

        short8 af[2], bf[4];
#pragma unroll
        for (int mt = 0; mt < 2; mt++)
            af[mt] = *(const short8*)&Asm[cur][(wm * 32 + mt * 16 + lr) * 32 + sq * 8];
#pragma unroll
        for (int nt = 0; nt < 4; nt++)
            bf[nt] = *(const short8*)&Bsm[cur][(wn * 64 + nt * 16 + lr) * 32 + sq * 8];
        __builtin_amdgcn_s_setprio(1);
#pragma unroll
        for (int mt = 0; mt < 2; mt++)
#pragma unroll
            for (int nt = 0; nt < 4; nt++)
                acc[mt][nt] = __builtin_amdgcn_mfma_f32_16x16x32_bf16(
                    af[mt], bf[nt], acc[mt][nt], 0, 0, 0);
        __builtin_amdgcn_s_setprio(0);
    }
#undef STAGE_S

    long long coff = bq * sC1 + hq * sC2;
    int bm = by * 64, bn = bx * 128;
    unsigned short* Cb = C + coff;

#pragma unroll
    for (int mt = 0; mt < 2; mt++) {
#pragma unroll
        for (int nt = 0; nt < 4; nt++) {
            int row0 = bm + wm * 32 + mt * 16 + quad * 4;
            int col = bn + wn * 64 + nt * 16 + lr;
#pragma unroll
            for (int i = 0; i < 4; i++)
                Cb[(size_t)(row0 + i) * ldc + col] = f2bf(acc[mt][nt][i] * scale);
        }
    }
}

// ---------------------------------------------------------------------------
// Scan phase A
// ---------------------------------------------------------------------------
__global__ __launch_bounds__(256) void scan_a(
    const float* __restrict__ delta, const unsigned short* __restrict__ u,
    const float* __restrict__ xdbl, const float* __restrict__ A_log,
    float* __restrict__ Hc, float* __restrict__ sumdv)
{
    int gid = blockIdx.x * 256 + threadIdx.x;
    int c = gid >> 12;
    int bd = gid & 4095;
    int b = bd >> 10, d = bd & 1023;

    float a[16];
#pragma unroll
    for (int j = 0; j < 4; j++) {
        float4 al = *(const float4*)(A_log + d * 16 + j * 4);
        a[j * 4 + 0] = -__expf(al.x); a[j * 4 + 1] = -__expf(al.y);
        a[j * 4 + 2] = -__expf(al.z); a[j * 4 + 3] = -__expf(al.w);
    }
    float h[16];
#pragma unroll
    for (int n = 0; n < 16; n++) h[n] = 0.f;
    float sd = 0.f;

    int t0 = c * CHL;
    const float* dp = delta + ((size_t)(b * L_) + t0) * DI + d;
    const unsigned short* up = u + ((size_t)(b * L_) + t0) * DI + d;
    const float* xp = xdbl + ((size_t)(b * L_) + t0) * 128;

#pragma unroll 4
    for (int t = 0; t < CHL; t++) {
        float dv = dp[t * DI];
        float uv = bf2f(up[t * DI]);
        float duv = dv * uv;
        sd += dv;
        float Bv[16];
#pragma unroll
        for (int j = 0; j < 4; j++) {
            float4 bq = *(const float4*)(xp + t * 128 + 64 + j * 4);
            Bv[j * 4 + 0] = bq.x; Bv[j * 4 + 1] = bq.y;
            Bv[j * 4 + 2] = bq.z; Bv[j * 4 + 3] = bq.w;
        }
#pragma unroll
        for (int n = 0; n < 16; n++)
            h[n] = __expf(dv * a[n]) * h[n] + duv * Bv[n];
    }

    float* hp = Hc + ((size_t)c * 4096 + bd) * 16;
#pragma unroll
    for (int j = 0; j < 4; j++)
        *(float4*)(hp + j * 4) = make_float4(h[j * 4], h[j * 4 + 1], h[j * 4 + 2], h[j * 4 + 3]);
    sumdv[c * 4096 + bd] = sd;
}

// ---------------------------------------------------------------------------
// Scan phase B
// ---------------------------------------------------------------------------
__global__ __launch_bounds__(256) void scan_b(
    float* __restrict__ Hc, const float* __restrict__ sumdv,
    const float* __restrict__ A_log)
{
    int bd = blockIdx.x * 256 + threadIdx.x;
    int d = bd & 1023;

    float a[16];
#pragma unroll
    for (int j = 0; j < 4; j++) {
        float4 al = *(const float4*)(A_log + d * 16 + j * 4);
        a[j * 4 + 0] = -__expf(al.x); a[j * 4 + 1] = -__expf(al.y);
        a[j * 4 + 2] = -__expf(al.z); a[j * 4 + 3] = -__expf(al.w);
    }
    float H[16];
#pragma unroll
    for (int n = 0; n < 16; n++) H[n] = 0.f;

    for (int c = 0; c < NCH; c++) {
        float* hp = Hc + ((size_t)c * 4096 + bd) * 16;
        float sdv = sumdv[c * 4096 + bd];
        float hc[16];
#pragma unroll
        for (int j = 0; j < 4; j++) {
            float4 q = *(const float4*)(hp + j * 4);
            hc[j * 4 + 0] = q.x; hc[j * 4 + 1] = q.y; hc[j * 4 + 2] = q.z; hc[j * 4 + 3] = q.w;
        }
#pragma unroll
        for (int j = 0; j < 4; j++)
            *(float4*)(hp + j * 4) = make_float4(H[j * 4], H[j * 4 + 1], H[j * 4 + 2], H[j * 4 + 3]);
#pragma unroll
        for (int n = 0; n < 16; n++)
            H[n] = __expf(a[n] * sdv) * H[n] + hc[n];
    }
}

// ---------------------------------------------------------------------------
// Scan phase C
// ---------------------------------------------------------------------------
__global__ __launch_bounds__(256) void scan_c(
    const float* __restrict__ delta, const unsigned short* __restrict__ u,
    const float* __restrict__ xdbl, const float* __restrict__ A_log,
    const float* __restrict__ Dv, const float* __restrict__ Hstart,
    unsigned short* __restrict__ y)
{
    int gid = blockIdx.x * 256 + threadIdx.x;
    int c = gid >> 12;
    int bd = gid & 4095;
    int b = bd >> 10, d = bd & 1023;

    float a[16];
#pragma unroll
    for (int j = 0; j < 4; j++) {
        float4 al = *(const float4*)(A_log + d * 16 + j * 4);
        a[j * 4 + 0] = -__expf(al.x); a[j * 4 + 1] = -__expf(al.y);
        a[j * 4 + 2] = -__expf(al.z); a[j * 4 + 3] = -__expf(al.w);
    }
    float h[16];
    const float* hp = Hstart + ((size_t)c * 4096 + bd) * 16;
#pragma unroll
    for (int j = 0; j < 4; j++) {
        float4 q = *(const float4*)(hp + j * 4);
        h[j * 4 + 0] = q.x; h[j * 4 + 1] = q.y; h[j * 4 + 2] = q.z; h[j * 4 + 3] = q.w;
    }
    float Dd = Dv[d];

    int t0 = c * CHL;
    const float* dp = delta + ((size_t)(b * L_) + t0) * DI + d;
    const unsigned short* up = u + ((size_t)(b * L_) + t0) * DI + d;
    const float* xp = xdbl + ((size_t)(b * L_) + t0) * 128;
    unsigned short* yp = y + ((size_t)(b * L_) + t0) * DI + d;

#pragma unroll 4
    for (int t = 0; t < CHL; t++) {
        float dv = dp[t * DI];
        float uv = bf2f(up[t * DI]);
        float duv = dv * uv;
        float Bv[16], Cv[16];
#pragma unroll
        for (int j = 0; j < 4; j++) {
            float4 bq = *(const float4*)(xp + t * 128 + 64 + j * 4);
            Bv[j * 4 + 0] = bq.x; Bv[j * 4 + 1] = bq.y;
            Bv[j * 4 + 2] = bq.z; Bv[j * 4 + 3] = bq.w;
            float4 cq = *(const float4*)(xp + t * 128 + 80 + j * 4);
            Cv[j * 4 + 0] = cq.x; Cv[j * 4 + 1] = cq.y;
            Cv[j * 4 + 2] = cq.z; Cv[j * 4 + 3] = cq.w;
        }
        float ys = 0.f;
#pragma unroll
        for (int n = 0; n < 16; n++) {
            h[n] = __expf(dv * a[n]) * h[n] + duv * Bv[n];
            ys += h[n] * Cv[n];
        }
        yp[t * DI] = f2bf(ys + uv * Dd);
    }
}

// ---------------------------------------------------------------------------
// Merged: row softmax over S (blocks 0..4095) + V->VT transpose
// (blocks 4096..8191). Independent work, one dispatch.
// ---------------------------------------------------------------------------
__global__ __launch_bounds__(256) void softmax_transpose(
    unsigned short* __restrict__ S,
    const unsigned short* __restrict__ V, unsigned short* __restrict__ VT)
{
    __shared__ unsigned short tl[32][36];
    int bid = blockIdx.x;
    if (bid < 4096) {
        int row = bid * 4 + (threadIdx.x >> 6);
        int lane = threadIdx.x & 63;
        unsigned short* p = S + (size_t)row * 1024;

        float v[16];
#pragma unroll
        for (int ch = 0; ch < 4; ch++) {
            ushort4 u4 = *(const ushort4*)(p + ch * 256 + lane * 4);
            v[ch * 4 + 0] = bf2f(u4.x); v[ch * 4 + 1] = bf2f(u4.y);
            v[ch * 4 + 2] = bf2f(u4.z); v[ch * 4 + 3] = bf2f(u4.w);
        }
        float m = -1e30f;
#pragma unroll
        for (int i = 0; i < 16; i++) m = fmaxf(m, v[i]);
#pragma unroll
        for (int off = 32; off >= 1; off >>= 1) m = fmaxf(m, __shfl_xor(m, off));
        float s = 0.f;
#pragma unroll
        for (int i = 0; i < 16; i++) { v[i] = __expf(v[i] - m); s += v[i]; }
#pragma unroll
        for (int off = 32; off >= 1; off >>= 1) s += __shfl_xor(s, off);
        float inv = 1.0f / s;
#pragma unroll
        for (int ch = 0; ch < 4; ch++) {
            ushort4 o;
            o.x = f2bf(v[ch * 4 + 0] * inv); o.y = f2bf(v[ch * 4 + 1] * inv);
            o.z = f2bf(v[ch * 4 + 2] * inv); o.w = f2bf(v[ch * 4 + 3] * inv);
            *(ushort4*)(p + ch * 256 + lane * 4) = o;
        }
        return;
    }
    int tb = bid - 4096;
    int bh = tb >> 8;
    int rem = tb & 255;
    int d0 = (rem >> 5) * 32;
    int l0 = (rem & 31) * 32;
    int b = bh >> 2, h = bh & 3;
    int tid = threadIdx.x;
    int r = tid >> 3, c4 = (tid & 7) * 4;

    const unsigned short* src = V + ((size_t)(b * L_ + l0 + r)) * 1024 + h * DK + d0 + c4;
    ushort4 v = *(const ushort4*)src;
    tl[r][c4 + 0] = v.x; tl[r][c4 + 1] = v.y; tl[r][c4 + 2] = v.z; tl[r][c4 + 3] = v.w;
    __syncthreads();

    unsigned short* dst = VT + ((size_t)bh * DK + d0 + r) * L_ + l0 + c4;
    ushort4 o;
    o.x = tl[c4 + 0][r]; o.y = tl[c4 + 1][r]; o.z = tl[c4 + 2][r]; o.w = tl[c4 + 3][r];
    *(ushort4*)dst = o;
}

// ---------------------------------------------------------------------------
extern "C" void kernel_launch(void* const* d_in, const int* in_sizes, int n_in,
                              void* d_out, int out_size, void* d_ws, size_t ws_size,
                              hipStream_t stream)
{
    const float* x         = (const float*)d_in[0];
    const float* xx        = (const float*)d_in[1];
    const float* in_proj_w = (const float*)d_in[2];
    const float* conv_w    = (const float*)d_in[3];
    const float* conv_b    = (const float*)d_in[4];
    const float* x_proj_w  = (const float*)d_in[5];
    const float* dt_proj_w = (const float*)d_in[6];
    const float* dt_proj_b = (const float*)d_in[7];
    const float* A_log     = (const float*)d_in[8];
    const float* Dvec      = (const float*)d_in[9];
    const float* wq        = (const float*)d_in[10];
    const float* bq        = (const float*)d_in[11];
    const float* wk        = (const float*)d_in[12];
    const float* bk        = (const float*)d_in[13];
    const float* wv        = (const float*)d_in[14];
    const float* bv        = (const float*)d_in[15];
    const float* wo        = (const float*)d_in[16];
    const float* bo        = (const float*)d_in[17];
    float* out = (float*)d_out;

    char* w = (char*)d_ws;
    const size_t MB = 1024 * 1024, KB = 1024;
    float*          Hc     = (float*)(w + 0);                // 8 MB (scan), dead after scan_c
    float*          delta  = (float*)(w + 16 * MB);          // 16 MB, dead after scan
    unsigned short* Sbuf   = (unsigned short*)(w + 0);       // 32 MB (after scan_c)
    unsigned short* x_bf   = (unsigned short*)(w + 32 * MB); // 8 MB (live thru step 7)
    unsigned short* Q_bf   = (unsigned short*)(w + 40 * MB); // 8 MB -> VT
    unsigned short* VT     = Q_bf;
    unsigned short* y_bf   = (unsigned short*)(w + 48 * MB); // 8 MB -> AO
    unsigned short* AO     = y_bf;
    unsigned short* K_bf   = (unsigned short*)(w + 56 * MB); // 8 MB
    unsigned short* V_bf   = (unsigned short*)(w + 64 * MB); // 8 MB
    unsigned short* u_bf   = (unsigned short*)(w + 72 * MB); // 8 MB (live thru scan_c)
    float*          xdbl   = (float*)(w + 80 * MB);          // 2 MB
    unsigned short* xdblb  = (unsigned short*)(w + 82 * MB); // 1 MB
    unsigned short* w_inT  = (unsigned short*)(w + 83 * MB); // 2 MB (in_proj_w^T bf16)
    unsigned short* w_q    = (unsigned short*)(w + 85 * MB); // 2 MB
    unsigned short* w_k    = (unsigned short*)(w + 87 * MB); // 2 MB
    unsigned short* w_v    = (unsigned short*)(w + 89 * MB); // 2 MB
    unsigned short* w_o    = (unsigned short*)(w + 91 * MB); // 2 MB
    unsigned short* w_xp   = (unsigned short*)(w + 93 * MB);            // 256 KB
    unsigned short* w_dt   = (unsigned short*)(w + 93 * MB + 256 * KB); // 128 KB
    float*          sumdv  = (float*)(w + 93 * MB + 384 * KB);          // 512 KB
    unsigned short* W_qin  = (unsigned short*)(w + 95 * MB); // 2 MB (wq @ W_in, bf16)

    dim3 blk(256);
    const long long LL = L_;

    // 1. prep: conv+silu (bf16 u only) + x cast + weight casts + in_proj_w^T
    PrepArgs pa;
    pa.xx = xx; pa.cw = conv_w; pa.cb = conv_b; pa.ub = u_bf;
    pa.xs = x; pa.xd = x_bf;
    pa.s[0] = wq;        pa.d[0] = w_q;  pa.n[0] = 1048576; pa.ns[0] = 1048576;
    pa.s[1] = wk;        pa.d[1] = w_k;  pa.n[1] = 1048576; pa.ns[1] = 1048576;
    pa.s[2] = wv;        pa.d[2] = w_v;  pa.n[2] = 1048576; pa.ns[2] = 1048576;
    pa.s[3] = wo;        pa.d[3] = w_o;  pa.n[3] = 1048576; pa.ns[3] = 1048576;
    pa.s[4] = x_proj_w;  pa.d[4] = w_xp; pa.n[4] = 131072;  pa.ns[4] = 98304;
    pa.s[5] = dt_proj_w; pa.d[5] = w_dt; pa.n[5] = 65536;   pa.ns[5] = 65536;
    pa.tsrc = in_proj_w; pa.tdst = w_inT;
    prep<<<dim3(25792), blk, 0, stream>>>(pa);

    // 2. W_qin = wq @ W_in (fold, M=1024 -> 64-tiles gy=16) || x_proj (gy=64)
    {
        GArgs ga = {};
        ga.g[0] = (GDesc){w_q, w_inT, nullptr, nullptr, W_qin,
                          1024, 1024, 1024, 1024, 0, 1, 1.0f, 8, 16};
        ga.g[1] = (GDesc){u_bf, w_xp, nullptr, xdbl, xdblb,
                          1024, 1024, 1024, 128, 128, 2, 1.0f, 1, 64};
        gemm_multi64<<<dim3(8, 64, 2), blk, 0, stream>>>(ga);
    }
    // 3. dt_proj (softplus), 64-tiles: gy=64 -> 512 blocks (2/CU)
    {
        GArgs ga = {};
        ga.g[0] = (GDesc){xdblb, w_dt, dt_proj_b, delta, nullptr,
                          64, 128, 64, 1024, 0, 0 | 4, 1.0f, 8, 64};
        gemm_multi64<<<dim3(8, 64, 1), blk, 0, stream>>>(ga);
    }
    // 4-6. chunked scan
    scan_a<<<dim3(512), blk, 0, stream>>>(delta, u_bf, xdbl, A_log, Hc, sumdv);
    scan_b<<<dim3(16), blk, 0, stream>>>(Hc, sumdv, A_log);
    scan_c<<<dim3(512), blk, 0, stream>>>(delta, u_bf, xdbl, A_log, Dvec, Hc, y_bf);

    // 7. Q (folded) || K || V projections (128² kernel, 3/CU — port-bound)
    {
        GArgs ga = {};
        ga.g[0] = (GDesc){x_bf, W_qin, bq, nullptr, Q_bf, 1024, 1024, 1024, 1024, 0, 1, 1.0f, 8, 32};
        ga.g[1] = (GDesc){y_bf, w_k, bk, nullptr, K_bf, 1024, 1024, 1024, 1024, 0, 1, 1.0f, 8, 32};
        ga.g[2] = (GDesc){y_bf, w_v, bv, nullptr, V_bf, 1024, 1024, 1024, 1024, 0, 1, 1.0f, 8, 32};
        gemm_multi<<<dim3(8, 32, 3), blk, 0, stream>>>(ga);
    }
    // 8. S = Q @ K^T * scale (128² batched, 4/CU grid)
    gemm_batched<<<dim3(8, 8, 16), blk, 0, stream>>>(Q_bf, K_bf, Sbuf,
        DK, 1024, 1024, 1024,
        LL * 1024, 256, LL * 1024, 256,
        4 * LL * 1024, LL * 1024, 0.0625f);
    // 9+10. softmax || V transpose (VT overwrites Q_bf, consumed by step 8)
    softmax_transpose<<<dim3(8192), blk, 0, stream>>>(Sbuf, V_bf, VT);
    // 11. AO = P @ V (64-tile batched: 2x16x16 = 512 blocks, 2/CU)
    gemm_batched64<<<dim3(2, 16, 16), blk, 0, stream>>>(Sbuf, VT, AO,
        1024, 1024, 1024, 1024,
        4 * LL * 1024, LL * 1024,
        4 * (long long)DK * 1024, (long long)DK * 1024,
        LL * 1024, 256, 1.0f);
    // 12. out = AO @ wo^T + bo (64-tile: 8x64 = 512 blocks, 2/CU)
    {
        GArgs ga = {};
        ga.g[0] = (GDesc){AO, w_o, bo, out, nullptr, 1024, 1024, 1024, 1024, 0, 0, 1.0f, 8, 64};
        gemm_multi64<<<dim3(8, 64, 1), blk, 0, stream>>>(ga);
    }
}